// Round 13
// baseline (272.702 us; speedup 1.0000x reference)
//
#include <hip/hip_runtime.h>
#include <hip/hip_fp16.h>

#define NN 50000
#define NE 800000
#define NG 8
#define BN_EPS 1e-5f
#define NBLK ((NN + 255) / 256)
#define NPART 8
#define HLD 192   // dedup'd H row width: [c0|c1|c2]

typedef __attribute__((ext_vector_type(8))) short bf16x8;
typedef __attribute__((ext_vector_type(4))) float f32x4;

static __device__ __forceinline__ unsigned short f2bf(float f) {
    unsigned int u = __float_as_uint(f);
    unsigned int r = (u + 0x7FFFu + ((u >> 16) & 1u)) >> 16;   // RNE
    return (unsigned short)r;
}
static __device__ __forceinline__ float bf2f(unsigned short h) {
    return __uint_as_float((unsigned int)h << 16);
}

// ---------------- CSR build ----------------

__global__ __launch_bounds__(256) void count_deg(const int4* __restrict__ dst4,
                                                 int* __restrict__ degi) {
    int t = blockIdx.x * 256 + threadIdx.x;
    if (t < NE / 4) {
        int4 d = dst4[t];
        atomicAdd(&degi[d.x], 1);
        atomicAdd(&degi[d.y], 1);
        atomicAdd(&degi[d.z], 1);
        atomicAdd(&degi[d.w], 1);
    }
}

__global__ __launch_bounds__(256) void scan_partial(const int* __restrict__ degi,
                                                    const float* __restrict__ x,
                                                    int* __restrict__ rowptr,
                                                    int* __restrict__ bsum,
                                                    float* __restrict__ dinv,
                                                    float* __restrict__ xs) {
    __shared__ int sh[256];
    const int tid = threadIdx.x;
    const int i = blockIdx.x * 256 + tid;
    int v = (i < NN) ? degi[i] : 0;
    if (i < NN) {
        float di = rsqrtf((float)(v + 1));
        dinv[i] = di;
        xs[i * 3 + 0] = x[i * 3 + 0] * di;
        xs[i * 3 + 1] = x[i * 3 + 1] * di;
        xs[i * 3 + 2] = x[i * 3 + 2] * di;
    }
    sh[tid] = v;
    __syncthreads();
#pragma unroll
    for (int off = 1; off < 256; off <<= 1) {
        int t = (tid >= off) ? sh[tid - off] : 0;
        __syncthreads();
        sh[tid] += t;
        __syncthreads();
    }
    if (i < NN) rowptr[i] = sh[tid] - v;
    if (tid == 255) bsum[blockIdx.x] = sh[255];
}

__global__ __launch_bounds__(256) void scan_bsums(int* __restrict__ bsum) {
    __shared__ int sh[256];
    const int tid = threadIdx.x;
    int v = (tid < NBLK) ? bsum[tid] : 0;
    sh[tid] = v;
    __syncthreads();
#pragma unroll
    for (int off = 1; off < 256; off <<= 1) {
        int t = (tid >= off) ? sh[tid - off] : 0;
        __syncthreads();
        sh[tid] += t;
        __syncthreads();
    }
    if (tid < NBLK) bsum[tid] = sh[tid] - v;
}

__global__ __launch_bounds__(256) void scan_finalize(const int* __restrict__ bsum,
                                                     int* __restrict__ rowptr,
                                                     int* __restrict__ cursor) {
    const int i = blockIdx.x * 256 + threadIdx.x;
    if (i < NN) {
        int r = rowptr[i] + bsum[blockIdx.x];
        rowptr[i] = r;
        cursor[i] = r;
    }
    if (i == 0) rowptr[NN] = NE;
}

__global__ __launch_bounds__(256) void fill_csr(const int* __restrict__ src,
                                                const int* __restrict__ dst,
                                                int* __restrict__ cursor,
                                                unsigned short* __restrict__ esrc16) {
    int e = blockIdx.x * 256 + threadIdx.x;
    if (e < NE) {
        int s = src[e], d = dst[e];
        int p = atomicAdd(&cursor[d], 1);
        esrc16[p] = (unsigned short)s;
    }
}

// ---------------- fused W pack (+ gfeat_part zeroing) ----------------

static __device__ __forceinline__ void pack_one(const float* W, int NOUT, int li,
                                                float v_override, bool use_override,
                                                unsigned short* ph, unsigned short* pl) {
    int j = li & 7;
    int lane = (li >> 3) & 63;
    int rest = li >> 9;
    int NF = NOUT >> 4;
    int f = rest % NF, ks = rest / NF;
    int k = ks * 32 + (lane >> 4) * 8 + j;
    int col = f * 16 + (lane & 15);
    float v = use_override ? v_override : W[k * NOUT + col];
    unsigned short hi = f2bf(v);
    ph[li] = hi;
    pl[li] = f2bf(v - bf2f(hi));
}

__global__ __launch_bounds__(256) void pack_all(
        const float* __restrict__ W1, const float* __restrict__ W2,
        const float* __restrict__ We0, const float* __restrict__ We1,
        unsigned short* __restrict__ Wp1h, unsigned short* __restrict__ Wp1l,
        unsigned short* __restrict__ Wp2h, unsigned short* __restrict__ Wp2l,
        unsigned short* __restrict__ We0h, unsigned short* __restrict__ We0l,
        unsigned short* __restrict__ We1h, unsigned short* __restrict__ We1l,
        float* __restrict__ gfeat_part) {
    int idx = blockIdx.x * 256 + threadIdx.x;
    if (idx < NPART * NG * 64) gfeat_part[idx] = 0.0f;
    if (idx < 4096) {
        pack_one(W1, 64, idx, 0.f, false, Wp1h, Wp1l);
    } else if (idx < 12288) {
        pack_one(W2, 64, idx - 4096, 0.f, false, Wp2h, Wp2l);
    } else if (idx < 36864) {
        int li = idx - 12288;
        int j = li & 7;
        int lane = (li >> 3) & 63;
        int rest = li >> 9;
        int f = rest % 8, ks = rest / 8;
        int k = ks * 32 + (lane >> 4) * 8 + j;
        int col = f * 16 + (lane & 15);
        float v = (k < 64) ? (We0[k * 128 + col] + We0[(k + 64) * 128 + col])
                           : We0[(k + 64) * 128 + col];
        pack_one(nullptr, 128, li, v, true, We0h, We0l);
    } else if (idx < 45056) {
        pack_one(We1, 64, idx - 36864, 0.f, false, We1h, We1l);
    }
}

// ---------------- split-bf16 MFMA GEMM -> fp16 gather table, half-split layout ----------------
// tab layout: [2][NN][32] fp16 (half h covers channels 32h..32h+31); 64B rows.

template<int K>
__global__ __launch_bounds__(256, 2) void mfma_tab(
        const unsigned short* __restrict__ Ahi,
        const unsigned short* __restrict__ Alo, int lda,
        const unsigned short* __restrict__ Bph,
        const unsigned short* __restrict__ Bpl,
        const float* __restrict__ dinv,
        __half* __restrict__ outH) {
    constexpr int KS = K / 32;
    const int wave = threadIdx.x >> 6;
    const int lane = threadIdx.x & 63;
    const int rbase = blockIdx.x * 64 + wave * 16;
    int arow = rbase + (lane & 15);
    if (arow >= NN) arow = NN - 1;
    const int kbase = (lane >> 4) * 8;

    bf16x8 bh[KS][4], bl[KS][4];
#pragma unroll
    for (int ks = 0; ks < KS; ks++)
#pragma unroll
        for (int f = 0; f < 4; f++) {
            bh[ks][f] = *reinterpret_cast<const bf16x8*>(Bph + (size_t)((ks * 4 + f) * 64 + lane) * 8);
            bl[ks][f] = *reinterpret_cast<const bf16x8*>(Bpl + (size_t)((ks * 4 + f) * 64 + lane) * 8);
        }

    const unsigned short* pa_hi = Ahi + (size_t)arow * lda + kbase;
    const unsigned short* pa_lo = Alo + (size_t)arow * lda + kbase;
    bf16x8 ah[KS], al[KS];
#pragma unroll
    for (int ks = 0; ks < KS; ks++) {
        ah[ks] = *reinterpret_cast<const bf16x8*>(pa_hi + ks * 32);
        al[ks] = *reinterpret_cast<const bf16x8*>(pa_lo + ks * 32);
    }

    f32x4 acc[4];
#pragma unroll
    for (int f = 0; f < 4; f++) acc[f] = (f32x4){0.f, 0.f, 0.f, 0.f};

#pragma unroll
    for (int ks = 0; ks < KS; ks++)
#pragma unroll
        for (int f = 0; f < 4; f++) {
            acc[f] = __builtin_amdgcn_mfma_f32_16x16x32_bf16(ah[ks], bh[ks][f], acc[f], 0, 0, 0);
            acc[f] = __builtin_amdgcn_mfma_f32_16x16x32_bf16(ah[ks], bl[ks][f], acc[f], 0, 0, 0);
            acc[f] = __builtin_amdgcn_mfma_f32_16x16x32_bf16(al[ks], bh[ks][f], acc[f], 0, 0, 0);
        }

    const int drow0 = rbase + (lane >> 4) * 4;
    const int dcol = lane & 15;
#pragma unroll
    for (int f = 0; f < 4; f++) {
#pragma unroll
        for (int r = 0; r < 4; r++) {
            int row = drow0 + r;
            if (row < NN)
                outH[(size_t)(f >> 1) * (NN * 32) + (size_t)row * 32 + (f & 1) * 16 + dcol]
                    = __float2half(acc[f][r] * dinv[row]);
        }
    }
}

// ---------------- fused encoder (enc0 -> LDS -> enc1) + pooling ----------------

__global__ __launch_bounds__(256, 2) void enc_fused(
        const unsigned short* __restrict__ Hhi,
        const unsigned short* __restrict__ Hlo,
        const unsigned short* __restrict__ We0h, const unsigned short* __restrict__ We0l,
        const float* __restrict__ b0,
        const unsigned short* __restrict__ We1h, const unsigned short* __restrict__ We1l,
        const float* __restrict__ b1,
        const int* __restrict__ batch,
        float* __restrict__ gfeat_part) {
    __shared__ float ldsT[4][16][133];
    __shared__ float poolw[4][64];
    __shared__ float pool[NG][64];
    const int tid = threadIdx.x;
    const int wave = tid >> 6;
    const int lane = tid & 63;
    const int rbase = blockIdx.x * 64 + wave * 16;

    // ---- stage A: T = relu(H @ We0 + b0), K=192, NF=8, B double-buffered ----
    int arow = rbase + (lane & 15);
    if (arow >= NN) arow = NN - 1;
    const int kbase = (lane >> 4) * 8;
    f32x4 acc[8];
#pragma unroll
    for (int f = 0; f < 8; f++) acc[f] = (f32x4){0.f, 0.f, 0.f, 0.f};

    const unsigned short* pa_hi = Hhi + (size_t)arow * HLD + kbase;
    const unsigned short* pa_lo = Hlo + (size_t)arow * HLD + kbase;

    bf16x8 cbh[8], cbl[8], nbh[8], nbl[8];
#pragma unroll
    for (int f = 0; f < 8; f++) {
        cbh[f] = *reinterpret_cast<const bf16x8*>(We0h + (size_t)(f * 64 + lane) * 8);
        cbl[f] = *reinterpret_cast<const bf16x8*>(We0l + (size_t)(f * 64 + lane) * 8);
    }
#pragma unroll
    for (int ks = 0; ks < 6; ks++) {
        if (ks < 5) {
#pragma unroll
            for (int f = 0; f < 8; f++) {
                nbh[f] = *reinterpret_cast<const bf16x8*>(We0h + (size_t)(((ks + 1) * 8 + f) * 64 + lane) * 8);
                nbl[f] = *reinterpret_cast<const bf16x8*>(We0l + (size_t)(((ks + 1) * 8 + f) * 64 + lane) * 8);
            }
        }
        bf16x8 ah = *reinterpret_cast<const bf16x8*>(pa_hi + ks * 32);
        bf16x8 al = *reinterpret_cast<const bf16x8*>(pa_lo + ks * 32);
#pragma unroll
        for (int f = 0; f < 8; f++) {
            acc[f] = __builtin_amdgcn_mfma_f32_16x16x32_bf16(ah, cbh[f], acc[f], 0, 0, 0);
            acc[f] = __builtin_amdgcn_mfma_f32_16x16x32_bf16(ah, cbl[f], acc[f], 0, 0, 0);
            acc[f] = __builtin_amdgcn_mfma_f32_16x16x32_bf16(al, cbh[f], acc[f], 0, 0, 0);
        }
        if (ks < 5) {
#pragma unroll
            for (int f = 0; f < 8; f++) { cbh[f] = nbh[f]; cbl[f] = nbl[f]; }
        }
    }

    const int lrow0 = (lane >> 4) * 4;
    const int dcol = lane & 15;
#pragma unroll
    for (int f = 0; f < 8; f++) {
#pragma unroll
        for (int r = 0; r < 4; r++) {
            float v = fmaxf(acc[f][r] + b0[f * 16 + dcol], 0.0f);
            ldsT[wave][lrow0 + r][f * 16 + dcol] = v;
        }
    }
    __syncthreads();

    // ---- stage B: out = relu(T @ We1 + b1), K=128, NF=4; We1 hoisted ----
    bf16x8 wbh[4][4], wbl[4][4];
#pragma unroll
    for (int ks = 0; ks < 4; ks++)
#pragma unroll
        for (int f = 0; f < 4; f++) {
            wbh[ks][f] = *reinterpret_cast<const bf16x8*>(We1h + (size_t)((ks * 4 + f) * 64 + lane) * 8);
            wbl[ks][f] = *reinterpret_cast<const bf16x8*>(We1l + (size_t)((ks * 4 + f) * 64 + lane) * 8);
        }

    f32x4 acc2[4];
#pragma unroll
    for (int f = 0; f < 4; f++) acc2[f] = (f32x4){0.f, 0.f, 0.f, 0.f};

    const int trow = lane & 15;
#pragma unroll
    for (int ks = 0; ks < 4; ks++) {
        bf16x8 ah, al;
#pragma unroll
        for (int j = 0; j < 8; j++) {
            float tv = ldsT[wave][trow][ks * 32 + (lane >> 4) * 8 + j];
            unsigned short hi = f2bf(tv);
            ah[j] = (short)hi;
            al[j] = (short)f2bf(tv - bf2f(hi));
        }
#pragma unroll
        for (int f = 0; f < 4; f++) {
            acc2[f] = __builtin_amdgcn_mfma_f32_16x16x32_bf16(ah, wbh[ks][f], acc2[f], 0, 0, 0);
            acc2[f] = __builtin_amdgcn_mfma_f32_16x16x32_bf16(ah, wbl[ks][f], acc2[f], 0, 0, 0);
            acc2[f] = __builtin_amdgcn_mfma_f32_16x16x32_bf16(al, wbh[ks][f], acc2[f], 0, 0, 0);
        }
    }

    // ---- epilogue: bias+relu, pool ----
    float vout[4][4];
#pragma unroll
    for (int f = 0; f < 4; f++)
#pragma unroll
        for (int r = 0; r < 4; r++) {
            int row = rbase + lrow0 + r;
            vout[f][r] = (row < NN) ? fmaxf(acc2[f][r] + b1[f * 16 + dcol], 0.0f) : 0.0f;
        }

    const int blk_row0 = blockIdx.x * 64;
    const int blk_rowN = min(blk_row0 + 63, NN - 1);
    const int g0 = batch[blk_row0];
    const int p = blockIdx.x & (NPART - 1);

    if (g0 == batch[blk_rowN]) {
#pragma unroll
        for (int f = 0; f < 4; f++) {
            float s = (vout[f][0] + vout[f][1]) + (vout[f][2] + vout[f][3]);
            s += __shfl_xor(s, 16, 64);
            s += __shfl_xor(s, 32, 64);
            if ((lane >> 4) == 0) poolw[wave][f * 16 + dcol] = s;
        }
        __syncthreads();
        if (tid < 64) {
            float s = (poolw[0][tid] + poolw[1][tid]) + (poolw[2][tid] + poolw[3][tid]);
            atomicAdd(&gfeat_part[(p * NG + g0) * 64 + tid], s);
        }
    } else {
        for (int i = tid; i < NG * 64; i += 256) ((float*)pool)[i] = 0.0f;
        __syncthreads();
#pragma unroll
        for (int r = 0; r < 4; r++) {
            int row = rbase + lrow0 + r;
            if (row < NN) {
                int g = batch[row];
#pragma unroll
                for (int f = 0; f < 4; f++)
                    atomicAdd(&pool[g][f * 16 + dcol], vout[f][r]);
            }
        }
        __syncthreads();
        for (int i = tid; i < NG * 64; i += 256) {
            float s = ((float*)pool)[i];
            if (s != 0.0f) atomicAdd(&gfeat_part[p * NG * 64 + i], s);
        }
    }
}

// ---------------- layer 0: aggregate xs (3-wide, pre-scaled) per node ----------------

__global__ __launch_bounds__(256) void agg_x3(
        const float* __restrict__ xs,
        const int* __restrict__ rowptr,
        const unsigned short* __restrict__ esrc16,
        const float* __restrict__ dinv,
        float* __restrict__ ax) {
    const int i = blockIdx.x * 256 + threadIdx.x;
    if (i >= NN) return;
    float a0 = xs[i * 3 + 0];
    float a1 = xs[i * 3 + 1];
    float a2 = xs[i * 3 + 2];
    const int beg = rowptr[i], end = rowptr[i + 1];
    int e = beg;
    for (; e + 3 < end; e += 4) {
        int s0 = esrc16[e], s1 = esrc16[e + 1], s2 = esrc16[e + 2], s3 = esrc16[e + 3];
        a0 += xs[s0 * 3 + 0] + xs[s1 * 3 + 0] + xs[s2 * 3 + 0] + xs[s3 * 3 + 0];
        a1 += xs[s0 * 3 + 1] + xs[s1 * 3 + 1] + xs[s2 * 3 + 1] + xs[s3 * 3 + 1];
        a2 += xs[s0 * 3 + 2] + xs[s1 * 3 + 2] + xs[s2 * 3 + 2] + xs[s3 * 3 + 2];
    }
    for (; e < end; e++) {
        int s = esrc16[e];
        a0 += xs[s * 3 + 0];
        a1 += xs[s * 3 + 1];
        a2 += xs[s * 3 + 2];
    }
    const float di = dinv[i];
    ax[i * 3 + 0] = a0 * di;
    ax[i * 3 + 1] = a1 * di;
    ax[i * 3 + 2] = a2 * di;
}

// ---------------- layer 0 dense -> H cols 0:64 ----------------

__global__ __launch_bounds__(256) void l0_bn_relu(
        const float* __restrict__ ax, const float* __restrict__ W0,
        const float* __restrict__ b, const float* __restrict__ g,
        const float* __restrict__ beta, const float* __restrict__ rm,
        const float* __restrict__ rv,
        unsigned short* __restrict__ Hhi, unsigned short* __restrict__ Hlo) {
    const int t = blockIdx.x * 256 + threadIdx.x;
    const int row = t >> 6;
    const int ch = t & 63;
    if (row >= NN) return;
    float a0 = ax[row * 3 + 0], a1 = ax[row * 3 + 1], a2 = ax[row * 3 + 2];
    float v = a0 * W0[0 * 64 + ch] + a1 * W0[1 * 64 + ch] + a2 * W0[2 * 64 + ch] + b[ch];
    float sc = g[ch] * rsqrtf(rv[ch] + BN_EPS);
    v = (v - rm[ch]) * sc + beta[ch];
    v = fmaxf(v, 0.0f);
    unsigned short hi = f2bf(v);
    Hhi[(size_t)row * HLD + ch] = hi;
    Hlo[(size_t)row * HLD + ch] = f2bf(v - bf2f(hi));
}

// ---------------- half-table gather + BN + ReLU -> hi/lo H slice ----------------
// tab2: [NN][16] half2 for ONE 32-channel half (3.2MB -> per-XCD L2 resident).
// Wave = 4 edge-groups x 16 lanes x 2ch. Two sequential launches per layer.

__global__ __launch_bounds__(256) void gather_bn_relu_h(
        const __half2* __restrict__ tab2,
        const int* __restrict__ rowptr,
        const unsigned short* __restrict__ esrc16,
        const float* __restrict__ dinv,
        const float* __restrict__ b, const float* __restrict__ g,
        const float* __restrict__ beta, const float* __restrict__ rm,
        const float* __restrict__ rv,
        unsigned short* __restrict__ Hhi, unsigned short* __restrict__ Hlo,
        int cbase, int choff) {
    const int wid = (blockIdx.x * 256 + threadIdx.x) >> 6;
    const int lane = threadIdx.x & 63;
    const int c2 = lane & 15;        // half2 idx within the 32-ch half
    const int grp = lane >> 4;       // 0..3, alternate edges
    if (wid >= NN) return;
    const int beg = rowptr[wid], end = rowptr[wid + 1];
    float a0 = 0.0f, a1 = 0.0f;
    int e = beg + grp;
    for (; e + 12 < end; e += 16) {
        int s0 = esrc16[e], s1 = esrc16[e + 4], s2 = esrc16[e + 8], s3 = esrc16[e + 12];
        float2 f0 = __half22float2(tab2[(size_t)s0 * 16 + c2]);
        float2 f1 = __half22float2(tab2[(size_t)s1 * 16 + c2]);
        float2 f2 = __half22float2(tab2[(size_t)s2 * 16 + c2]);
        float2 f3 = __half22float2(tab2[(size_t)s3 * 16 + c2]);
        a0 += (f0.x + f1.x) + (f2.x + f3.x);
        a1 += (f0.y + f1.y) + (f2.y + f3.y);
    }
    for (; e < end; e += 4) {
        float2 f = __half22float2(tab2[(size_t)esrc16[e] * 16 + c2]);
        a0 += f.x;
        a1 += f.y;
    }
    a0 += __shfl_xor(a0, 16, 64);
    a0 += __shfl_xor(a0, 32, 64);
    a1 += __shfl_xor(a1, 16, 64);
    a1 += __shfl_xor(a1, 32, 64);
    float2 fs = __half22float2(tab2[(size_t)wid * 16 + c2]);  // self-loop
    a0 += fs.x;
    a1 += fs.y;
    const float di = dinv[wid];
    a0 *= di;
    a1 *= di;
    const int ch0 = choff + 2 * c2, ch1 = ch0 + 1;   // layer-channel index
    float v0 = (a0 + b[ch0] - rm[ch0]) * (g[ch0] * rsqrtf(rv[ch0] + BN_EPS)) + beta[ch0];
    float v1 = (a1 + b[ch1] - rm[ch1]) * (g[ch1] * rsqrtf(rv[ch1] + BN_EPS)) + beta[ch1];
    v0 = fmaxf(v0, 0.0f);
    v1 = fmaxf(v1, 0.0f);
    if (grp == 0) {
        unsigned short h0 = f2bf(v0), h1 = f2bf(v1);
        unsigned short l0 = f2bf(v0 - bf2f(h0)), l1 = f2bf(v1 - bf2f(h1));
        size_t o = (size_t)wid * HLD + cbase + ch0;   // even -> 4B aligned
        *reinterpret_cast<unsigned int*>(&Hhi[o]) = (unsigned int)h0 | ((unsigned int)h1 << 16);
        *reinterpret_cast<unsigned int*>(&Hlo[o]) = (unsigned int)l0 | ((unsigned int)l1 << 16);
    }
}

// ---------------- decoder (counts via binary search on sorted batch) ----------------

__global__ __launch_bounds__(256) void dec_kernel(
        const float* __restrict__ gfeat_part, const int* __restrict__ batch,
        const float* __restrict__ w0, const float* __restrict__ b0,
        const float* __restrict__ w1, const float* __restrict__ b1,
        float* __restrict__ out) {
    __shared__ float mg[NG][64];
    __shared__ float mc[NG];
    __shared__ float t1[NG][32];
    const int tid = threadIdx.x;
    for (int idx = tid; idx < NG * 64; idx += 256) {
        float s = 0.0f;
#pragma unroll
        for (int p = 0; p < NPART; p++) s += gfeat_part[p * NG * 64 + idx];
        mg[idx >> 6][idx & 63] = s;
    }
    if (tid < NG) {
        int lo = 0, hi = NN;
        while (lo < hi) { int m = (lo + hi) >> 1; if (batch[m] < tid) lo = m + 1; else hi = m; }
        int s0 = lo;
        lo = 0; hi = NN;
        while (lo < hi) { int m = (lo + hi) >> 1; if (batch[m] < tid + 1) lo = m + 1; else hi = m; }
        mc[tid] = (float)(lo - s0);
    }
    __syncthreads();
    const int g = tid >> 5, c = tid & 31;
    float inv = 1.0f / fmaxf(mc[g], 1.0f);
    float acc = b0[c];
    for (int k = 0; k < 64; k++)
        acc = fmaf(mg[g][k] * inv, w0[k * 32 + c], acc);
    t1[g][c] = fmaxf(acc, 0.0f);
    __syncthreads();
    if (tid < NG) {
        float o = b1[0];
        for (int c2 = 0; c2 < 32; c2++) o = fmaf(t1[tid][c2], w1[c2], o);
        out[tid] = o;
    }
}

// ---------------- launch ----------------

extern "C" void kernel_launch(void* const* d_in, const int* in_sizes, int n_in,
                              void* d_out, int out_size, void* d_ws, size_t ws_size,
                              hipStream_t stream) {
    const float* x      = (const float*)d_in[0];
    const int*   ei     = (const int*)d_in[1];
    const int*   batch  = (const int*)d_in[2];
    const float* W0     = (const float*)d_in[3];
    const float* b0     = (const float*)d_in[4];
    const float* g0     = (const float*)d_in[5];
    const float* beta0  = (const float*)d_in[6];
    const float* rm0    = (const float*)d_in[7];
    const float* rv0    = (const float*)d_in[8];
    const float* W1     = (const float*)d_in[9];
    const float* b1     = (const float*)d_in[10];
    const float* g1     = (const float*)d_in[11];
    const float* beta1  = (const float*)d_in[12];
    const float* rm1    = (const float*)d_in[13];
    const float* rv1    = (const float*)d_in[14];
    const float* W2     = (const float*)d_in[15];
    const float* b2     = (const float*)d_in[16];
    const float* g2     = (const float*)d_in[17];
    const float* beta2  = (const float*)d_in[18];
    const float* rm2    = (const float*)d_in[19];
    const float* rv2    = (const float*)d_in[20];
    const float* enc_w0 = (const float*)d_in[21];
    const float* enc_b0 = (const float*)d_in[22];
    const float* enc_w1 = (const float*)d_in[23];
    const float* enc_b1 = (const float*)d_in[24];
    const float* dec_w0 = (const float*)d_in[25];
    const float* dec_b0 = (const float*)d_in[26];
    const float* dec_w1 = (const float*)d_in[27];
    const float* dec_b1 = (const float*)d_in[28];

    const int* esrc = ei;
    const int* edst = ei + NE;

    char* wsb = (char*)d_ws;
    unsigned short* Hhi = (unsigned short*)wsb;                       // [NN*192]
    unsigned short* Hlo = Hhi + (size_t)NN * HLD;                     // [NN*192]
    int*   degi   = (int*)(Hlo + (size_t)NN * HLD);                   // [NN]
    int*   rowptr = degi + NN;                                        // [NN+1]
    int*   cursor = rowptr + NN + 1;                                  // [NN]
    unsigned short* esrc16 = (unsigned short*)(cursor + NN);          // [NE] u16
    __half* tabh  = (__half*)(esrc16 + NE);                           // [2][NN][32] fp16
    float* dinv   = (float*)(tabh + (size_t)NN * 64);                 // [NN]
    float* xs     = dinv + NN;                                        // [NN*3]
    float* ax     = xs + (size_t)NN * 3;                              // [NN*3]
    float* gfeat_part = ax + (size_t)NN * 3;                          // [8*8*64]
    int*   bsum   = (int*)(gfeat_part + NPART * NG * 64);             // [NBLK]
    unsigned short* wp = (unsigned short*)(bsum + NBLK);
    unsigned short* Wp1h = wp;              unsigned short* Wp1l = Wp1h + 64 * 64;
    unsigned short* Wp2h = Wp1l + 64 * 64;  unsigned short* Wp2l = Wp2h + 128 * 64;
    unsigned short* We0h = Wp2l + 128 * 64; unsigned short* We0l = We0h + 192 * 128;
    unsigned short* We1h = We0l + 192 * 128;unsigned short* We1l = We1h + 128 * 64;

    hipMemsetAsync(degi, 0, NN * sizeof(int), stream);

    // CSR build
    count_deg<<<(NE / 4 + 255) / 256, 256, 0, stream>>>((const int4*)edst, degi);
    scan_partial<<<NBLK, 256, 0, stream>>>(degi, x, rowptr, bsum, dinv, xs);
    scan_bsums<<<1, 256, 0, stream>>>(bsum);
    scan_finalize<<<NBLK, 256, 0, stream>>>(bsum, rowptr, cursor);
    fill_csr<<<(NE + 255) / 256, 256, 0, stream>>>(esrc, edst, cursor, esrc16);

    pack_all<<<(45056 + 255) / 256, 256, 0, stream>>>(W1, W2, enc_w0, enc_w1,
                                                      Wp1h, Wp1l, Wp2h, Wp2l,
                                                      We0h, We0l, We1h, We1l, gfeat_part);

    const int GRID_MFMA = (NN + 63) / 64;
    const int GRID_64   = (NN * 64 + 255) / 256;
    const __half2* tab0 = (const __half2*)tabh;
    const __half2* tab1 = (const __half2*)(tabh + (size_t)NN * 32);

    // ---- layer 0 ----
    agg_x3<<<NBLK, 256, 0, stream>>>(xs, rowptr, esrc16, dinv, ax);
    l0_bn_relu<<<GRID_64, 256, 0, stream>>>(ax, W0, b0, g0, beta0, rm0, rv0, Hhi, Hlo);

    // ---- layer 1: table halves gathered sequentially (each 3.2MB, L2-resident) ----
    mfma_tab<64><<<GRID_MFMA, 256, 0, stream>>>(Hhi, Hlo, HLD, Wp1h, Wp1l, dinv, tabh);
    gather_bn_relu_h<<<GRID_64, 256, 0, stream>>>(tab0, rowptr, esrc16, dinv,
                                                  b1, g1, beta1, rm1, rv1, Hhi, Hlo, 64, 0);
    gather_bn_relu_h<<<GRID_64, 256, 0, stream>>>(tab1, rowptr, esrc16, dinv,
                                                  b1, g1, beta1, rm1, rv1, Hhi, Hlo, 64, 32);

    // ---- layer 2 ----
    mfma_tab<128><<<GRID_MFMA, 256, 0, stream>>>(Hhi, Hlo, HLD, Wp2h, Wp2l, dinv, tabh);
    gather_bn_relu_h<<<GRID_64, 256, 0, stream>>>(tab0, rowptr, esrc16, dinv,
                                                  b2, g2, beta2, rm2, rv2, Hhi, Hlo, 128, 0);
    gather_bn_relu_h<<<GRID_64, 256, 0, stream>>>(tab1, rowptr, esrc16, dinv,
                                                  b2, g2, beta2, rm2, rv2, Hhi, Hlo, 128, 32);

    // ---- fused encoder + pooling ----
    enc_fused<<<GRID_MFMA, 256, 0, stream>>>(Hhi, Hlo, We0h, We0l, enc_b0,
                                             We1h, We1l, enc_b1, batch, gfeat_part);

    // ---- decode ----
    dec_kernel<<<1, 256, 0, stream>>>(gfeat_part, batch, dec_w0, dec_b0, dec_w1, dec_b1, (float*)d_out);
}

// Round 14
// 235.819 us; speedup vs baseline: 1.1564x; 1.1564x over previous
//
#include <hip/hip_runtime.h>
#include <hip/hip_fp16.h>

#define NN 50000
#define NE 800000
#define NG 8
#define BN_EPS 1e-5f
#define NBLK ((NN + 255) / 256)
#define NPART 8
#define HLD 192   // dedup'd H row width: [c0|c1|c2]

typedef __attribute__((ext_vector_type(8))) short bf16x8;
typedef __attribute__((ext_vector_type(4))) float f32x4;

static __device__ __forceinline__ unsigned short f2bf(float f) {
    unsigned int u = __float_as_uint(f);
    unsigned int r = (u + 0x7FFFu + ((u >> 16) & 1u)) >> 16;   // RNE
    return (unsigned short)r;
}
static __device__ __forceinline__ float bf2f(unsigned short h) {
    return __uint_as_float((unsigned int)h << 16);
}

// ---------------- CSR build ----------------

__global__ __launch_bounds__(256) void count_deg(const int4* __restrict__ dst4,
                                                 int* __restrict__ degi) {
    int t = blockIdx.x * 256 + threadIdx.x;
    if (t < NE / 4) {
        int4 d = dst4[t];
        atomicAdd(&degi[d.x], 1);
        atomicAdd(&degi[d.y], 1);
        atomicAdd(&degi[d.z], 1);
        atomicAdd(&degi[d.w], 1);
    }
}

__global__ __launch_bounds__(256) void scan_partial(const int* __restrict__ degi,
                                                    const float* __restrict__ x,
                                                    int* __restrict__ rowptr,
                                                    int* __restrict__ bsum,
                                                    float* __restrict__ dinv,
                                                    float* __restrict__ xs) {
    __shared__ int sh[256];
    const int tid = threadIdx.x;
    const int i = blockIdx.x * 256 + tid;
    int v = (i < NN) ? degi[i] : 0;
    if (i < NN) {
        float di = rsqrtf((float)(v + 1));
        dinv[i] = di;
        xs[i * 3 + 0] = x[i * 3 + 0] * di;
        xs[i * 3 + 1] = x[i * 3 + 1] * di;
        xs[i * 3 + 2] = x[i * 3 + 2] * di;
    }
    sh[tid] = v;
    __syncthreads();
#pragma unroll
    for (int off = 1; off < 256; off <<= 1) {
        int t = (tid >= off) ? sh[tid - off] : 0;
        __syncthreads();
        sh[tid] += t;
        __syncthreads();
    }
    if (i < NN) rowptr[i] = sh[tid] - v;
    if (tid == 255) bsum[blockIdx.x] = sh[255];
}

__global__ __launch_bounds__(256) void scan_bsums(int* __restrict__ bsum) {
    __shared__ int sh[256];
    const int tid = threadIdx.x;
    int v = (tid < NBLK) ? bsum[tid] : 0;
    sh[tid] = v;
    __syncthreads();
#pragma unroll
    for (int off = 1; off < 256; off <<= 1) {
        int t = (tid >= off) ? sh[tid - off] : 0;
        __syncthreads();
        sh[tid] += t;
        __syncthreads();
    }
    if (tid < NBLK) bsum[tid] = sh[tid] - v;
}

__global__ __launch_bounds__(256) void scan_finalize(const int* __restrict__ bsum,
                                                     int* __restrict__ rowptr,
                                                     int* __restrict__ cursor) {
    const int i = blockIdx.x * 256 + threadIdx.x;
    if (i < NN) {
        int r = rowptr[i] + bsum[blockIdx.x];
        rowptr[i] = r;
        cursor[i] = r;
    }
    if (i == 0) rowptr[NN] = NE;
}

__global__ __launch_bounds__(256) void fill_csr(const int* __restrict__ src,
                                                const int* __restrict__ dst,
                                                int* __restrict__ cursor,
                                                unsigned short* __restrict__ esrc16) {
    int e = blockIdx.x * 256 + threadIdx.x;
    if (e < NE) {
        int s = src[e], d = dst[e];
        int p = atomicAdd(&cursor[d], 1);
        esrc16[p] = (unsigned short)s;
    }
}

// ---------------- fused W pack (+ gfeat_part zeroing) ----------------

static __device__ __forceinline__ void pack_one(const float* W, int NOUT, int li,
                                                float v_override, bool use_override,
                                                unsigned short* ph, unsigned short* pl) {
    int j = li & 7;
    int lane = (li >> 3) & 63;
    int rest = li >> 9;
    int NF = NOUT >> 4;
    int f = rest % NF, ks = rest / NF;
    int k = ks * 32 + (lane >> 4) * 8 + j;
    int col = f * 16 + (lane & 15);
    float v = use_override ? v_override : W[k * NOUT + col];
    unsigned short hi = f2bf(v);
    ph[li] = hi;
    pl[li] = f2bf(v - bf2f(hi));
}

__global__ __launch_bounds__(256) void pack_all(
        const float* __restrict__ W1, const float* __restrict__ W2,
        const float* __restrict__ We0, const float* __restrict__ We1,
        unsigned short* __restrict__ Wp1h, unsigned short* __restrict__ Wp1l,
        unsigned short* __restrict__ Wp2h, unsigned short* __restrict__ Wp2l,
        unsigned short* __restrict__ We0h, unsigned short* __restrict__ We0l,
        unsigned short* __restrict__ We1h, unsigned short* __restrict__ We1l,
        float* __restrict__ gfeat_part) {
    int idx = blockIdx.x * 256 + threadIdx.x;
    if (idx < NPART * NG * 64) gfeat_part[idx] = 0.0f;
    if (idx < 4096) {
        pack_one(W1, 64, idx, 0.f, false, Wp1h, Wp1l);
    } else if (idx < 12288) {
        pack_one(W2, 64, idx - 4096, 0.f, false, Wp2h, Wp2l);
    } else if (idx < 36864) {
        int li = idx - 12288;
        int j = li & 7;
        int lane = (li >> 3) & 63;
        int rest = li >> 9;
        int f = rest % 8, ks = rest / 8;
        int k = ks * 32 + (lane >> 4) * 8 + j;
        int col = f * 16 + (lane & 15);
        float v = (k < 64) ? (We0[k * 128 + col] + We0[(k + 64) * 128 + col])
                           : We0[(k + 64) * 128 + col];
        pack_one(nullptr, 128, li, v, true, We0h, We0l);
    } else if (idx < 45056) {
        pack_one(We1, 64, idx - 36864, 0.f, false, We1h, We1l);
    }
}

// ---------------- split-bf16 MFMA GEMM -> fp16 gather table ----------------

template<int K>
__global__ __launch_bounds__(256, 2) void mfma_tab(
        const unsigned short* __restrict__ Ahi,
        const unsigned short* __restrict__ Alo, int lda,
        const unsigned short* __restrict__ Bph,
        const unsigned short* __restrict__ Bpl,
        const float* __restrict__ dinv,
        __half* __restrict__ outH) {
    constexpr int KS = K / 32;
    const int wave = threadIdx.x >> 6;
    const int lane = threadIdx.x & 63;
    const int rbase = blockIdx.x * 64 + wave * 16;
    int arow = rbase + (lane & 15);
    if (arow >= NN) arow = NN - 1;
    const int kbase = (lane >> 4) * 8;

    bf16x8 bh[KS][4], bl[KS][4];
#pragma unroll
    for (int ks = 0; ks < KS; ks++)
#pragma unroll
        for (int f = 0; f < 4; f++) {
            bh[ks][f] = *reinterpret_cast<const bf16x8*>(Bph + (size_t)((ks * 4 + f) * 64 + lane) * 8);
            bl[ks][f] = *reinterpret_cast<const bf16x8*>(Bpl + (size_t)((ks * 4 + f) * 64 + lane) * 8);
        }

    const unsigned short* pa_hi = Ahi + (size_t)arow * lda + kbase;
    const unsigned short* pa_lo = Alo + (size_t)arow * lda + kbase;
    bf16x8 ah[KS], al[KS];
#pragma unroll
    for (int ks = 0; ks < KS; ks++) {
        ah[ks] = *reinterpret_cast<const bf16x8*>(pa_hi + ks * 32);
        al[ks] = *reinterpret_cast<const bf16x8*>(pa_lo + ks * 32);
    }

    f32x4 acc[4];
#pragma unroll
    for (int f = 0; f < 4; f++) acc[f] = (f32x4){0.f, 0.f, 0.f, 0.f};

#pragma unroll
    for (int ks = 0; ks < KS; ks++)
#pragma unroll
        for (int f = 0; f < 4; f++) {
            acc[f] = __builtin_amdgcn_mfma_f32_16x16x32_bf16(ah[ks], bh[ks][f], acc[f], 0, 0, 0);
            acc[f] = __builtin_amdgcn_mfma_f32_16x16x32_bf16(ah[ks], bl[ks][f], acc[f], 0, 0, 0);
            acc[f] = __builtin_amdgcn_mfma_f32_16x16x32_bf16(al[ks], bh[ks][f], acc[f], 0, 0, 0);
        }

    const int drow0 = rbase + (lane >> 4) * 4;
    const int dcol = lane & 15;
#pragma unroll
    for (int f = 0; f < 4; f++) {
#pragma unroll
        for (int r = 0; r < 4; r++) {
            int row = drow0 + r;
            if (row < NN)
                outH[(size_t)row * 64 + f * 16 + dcol] = __float2half(acc[f][r] * dinv[row]);
        }
    }
}

// ---------------- fused encoder (enc0 -> LDS -> enc1) + pooling ----------------

__global__ __launch_bounds__(256, 2) void enc_fused(
        const unsigned short* __restrict__ Hhi,
        const unsigned short* __restrict__ Hlo,
        const unsigned short* __restrict__ We0h, const unsigned short* __restrict__ We0l,
        const float* __restrict__ b0,
        const unsigned short* __restrict__ We1h, const unsigned short* __restrict__ We1l,
        const float* __restrict__ b1,
        const int* __restrict__ batch,
        float* __restrict__ gfeat_part) {
    __shared__ float ldsT[4][16][133];
    __shared__ float poolw[4][64];
    __shared__ float pool[NG][64];
    const int tid = threadIdx.x;
    const int wave = tid >> 6;
    const int lane = tid & 63;
    const int rbase = blockIdx.x * 64 + wave * 16;

    // ---- stage A: T = relu(H @ We0 + b0), K=192, NF=8, B double-buffered ----
    int arow = rbase + (lane & 15);
    if (arow >= NN) arow = NN - 1;
    const int kbase = (lane >> 4) * 8;
    f32x4 acc[8];
#pragma unroll
    for (int f = 0; f < 8; f++) acc[f] = (f32x4){0.f, 0.f, 0.f, 0.f};

    const unsigned short* pa_hi = Hhi + (size_t)arow * HLD + kbase;
    const unsigned short* pa_lo = Hlo + (size_t)arow * HLD + kbase;

    bf16x8 cbh[8], cbl[8], nbh[8], nbl[8];
#pragma unroll
    for (int f = 0; f < 8; f++) {
        cbh[f] = *reinterpret_cast<const bf16x8*>(We0h + (size_t)(f * 64 + lane) * 8);
        cbl[f] = *reinterpret_cast<const bf16x8*>(We0l + (size_t)(f * 64 + lane) * 8);
    }
#pragma unroll
    for (int ks = 0; ks < 6; ks++) {
        if (ks < 5) {
#pragma unroll
            for (int f = 0; f < 8; f++) {
                nbh[f] = *reinterpret_cast<const bf16x8*>(We0h + (size_t)(((ks + 1) * 8 + f) * 64 + lane) * 8);
                nbl[f] = *reinterpret_cast<const bf16x8*>(We0l + (size_t)(((ks + 1) * 8 + f) * 64 + lane) * 8);
            }
        }
        bf16x8 ah = *reinterpret_cast<const bf16x8*>(pa_hi + ks * 32);
        bf16x8 al = *reinterpret_cast<const bf16x8*>(pa_lo + ks * 32);
#pragma unroll
        for (int f = 0; f < 8; f++) {
            acc[f] = __builtin_amdgcn_mfma_f32_16x16x32_bf16(ah, cbh[f], acc[f], 0, 0, 0);
            acc[f] = __builtin_amdgcn_mfma_f32_16x16x32_bf16(ah, cbl[f], acc[f], 0, 0, 0);
            acc[f] = __builtin_amdgcn_mfma_f32_16x16x32_bf16(al, cbh[f], acc[f], 0, 0, 0);
        }
        if (ks < 5) {
#pragma unroll
            for (int f = 0; f < 8; f++) { cbh[f] = nbh[f]; cbl[f] = nbl[f]; }
        }
    }

    const int lrow0 = (lane >> 4) * 4;
    const int dcol = lane & 15;
#pragma unroll
    for (int f = 0; f < 8; f++) {
#pragma unroll
        for (int r = 0; r < 4; r++) {
            float v = fmaxf(acc[f][r] + b0[f * 16 + dcol], 0.0f);
            ldsT[wave][lrow0 + r][f * 16 + dcol] = v;
        }
    }
    __syncthreads();

    // ---- stage B: out = relu(T @ We1 + b1), K=128, NF=4; We1 hoisted ----
    bf16x8 wbh[4][4], wbl[4][4];
#pragma unroll
    for (int ks = 0; ks < 4; ks++)
#pragma unroll
        for (int f = 0; f < 4; f++) {
            wbh[ks][f] = *reinterpret_cast<const bf16x8*>(We1h + (size_t)((ks * 4 + f) * 64 + lane) * 8);
            wbl[ks][f] = *reinterpret_cast<const bf16x8*>(We1l + (size_t)((ks * 4 + f) * 64 + lane) * 8);
        }

    f32x4 acc2[4];
#pragma unroll
    for (int f = 0; f < 4; f++) acc2[f] = (f32x4){0.f, 0.f, 0.f, 0.f};

    const int trow = lane & 15;
#pragma unroll
    for (int ks = 0; ks < 4; ks++) {
        bf16x8 ah, al;
#pragma unroll
        for (int j = 0; j < 8; j++) {
            float tv = ldsT[wave][trow][ks * 32 + (lane >> 4) * 8 + j];
            unsigned short hi = f2bf(tv);
            ah[j] = (short)hi;
            al[j] = (short)f2bf(tv - bf2f(hi));
        }
#pragma unroll
        for (int f = 0; f < 4; f++) {
            acc2[f] = __builtin_amdgcn_mfma_f32_16x16x32_bf16(ah, wbh[ks][f], acc2[f], 0, 0, 0);
            acc2[f] = __builtin_amdgcn_mfma_f32_16x16x32_bf16(ah, wbl[ks][f], acc2[f], 0, 0, 0);
            acc2[f] = __builtin_amdgcn_mfma_f32_16x16x32_bf16(al, wbh[ks][f], acc2[f], 0, 0, 0);
        }
    }

    // ---- epilogue: bias+relu, pool ----
    float vout[4][4];
#pragma unroll
    for (int f = 0; f < 4; f++)
#pragma unroll
        for (int r = 0; r < 4; r++) {
            int row = rbase + lrow0 + r;
            vout[f][r] = (row < NN) ? fmaxf(acc2[f][r] + b1[f * 16 + dcol], 0.0f) : 0.0f;
        }

    const int blk_row0 = blockIdx.x * 64;
    const int blk_rowN = min(blk_row0 + 63, NN - 1);
    const int g0 = batch[blk_row0];
    const int p = blockIdx.x & (NPART - 1);

    if (g0 == batch[blk_rowN]) {
#pragma unroll
        for (int f = 0; f < 4; f++) {
            float s = (vout[f][0] + vout[f][1]) + (vout[f][2] + vout[f][3]);
            s += __shfl_xor(s, 16, 64);
            s += __shfl_xor(s, 32, 64);
            if ((lane >> 4) == 0) poolw[wave][f * 16 + dcol] = s;
        }
        __syncthreads();
        if (tid < 64) {
            float s = (poolw[0][tid] + poolw[1][tid]) + (poolw[2][tid] + poolw[3][tid]);
            atomicAdd(&gfeat_part[(p * NG + g0) * 64 + tid], s);
        }
    } else {
        for (int i = tid; i < NG * 64; i += 256) ((float*)pool)[i] = 0.0f;
        __syncthreads();
#pragma unroll
        for (int r = 0; r < 4; r++) {
            int row = rbase + lrow0 + r;
            if (row < NN) {
                int g = batch[row];
#pragma unroll
                for (int f = 0; f < 4; f++)
                    atomicAdd(&pool[g][f * 16 + dcol], vout[f][r]);
            }
        }
        __syncthreads();
        for (int i = tid; i < NG * 64; i += 256) {
            float s = ((float*)pool)[i];
            if (s != 0.0f) atomicAdd(&gfeat_part[p * NG * 64 + i], s);
        }
    }
}

// ---------------- layer 0: aggregate xs (3-wide, pre-scaled) per node ----------------

__global__ __launch_bounds__(256) void agg_x3(
        const float* __restrict__ xs,
        const int* __restrict__ rowptr,
        const unsigned short* __restrict__ esrc16,
        const float* __restrict__ dinv,
        float* __restrict__ ax) {
    const int i = blockIdx.x * 256 + threadIdx.x;
    if (i >= NN) return;
    float a0 = xs[i * 3 + 0];
    float a1 = xs[i * 3 + 1];
    float a2 = xs[i * 3 + 2];
    const int beg = rowptr[i], end = rowptr[i + 1];
    int e = beg;
    for (; e + 3 < end; e += 4) {
        int s0 = esrc16[e], s1 = esrc16[e + 1], s2 = esrc16[e + 2], s3 = esrc16[e + 3];
        a0 += xs[s0 * 3 + 0] + xs[s1 * 3 + 0] + xs[s2 * 3 + 0] + xs[s3 * 3 + 0];
        a1 += xs[s0 * 3 + 1] + xs[s1 * 3 + 1] + xs[s2 * 3 + 1] + xs[s3 * 3 + 1];
        a2 += xs[s0 * 3 + 2] + xs[s1 * 3 + 2] + xs[s2 * 3 + 2] + xs[s3 * 3 + 2];
    }
    for (; e < end; e++) {
        int s = esrc16[e];
        a0 += xs[s * 3 + 0];
        a1 += xs[s * 3 + 1];
        a2 += xs[s * 3 + 2];
    }
    const float di = dinv[i];
    ax[i * 3 + 0] = a0 * di;
    ax[i * 3 + 1] = a1 * di;
    ax[i * 3 + 2] = a2 * di;
}

// ---------------- layer 0 dense -> H cols 0:64 ----------------

__global__ __launch_bounds__(256) void l0_bn_relu(
        const float* __restrict__ ax, const float* __restrict__ W0,
        const float* __restrict__ b, const float* __restrict__ g,
        const float* __restrict__ beta, const float* __restrict__ rm,
        const float* __restrict__ rv,
        unsigned short* __restrict__ Hhi, unsigned short* __restrict__ Hlo) {
    const int t = blockIdx.x * 256 + threadIdx.x;
    const int row = t >> 6;
    const int ch = t & 63;
    if (row >= NN) return;
    float a0 = ax[row * 3 + 0], a1 = ax[row * 3 + 1], a2 = ax[row * 3 + 2];
    float v = a0 * W0[0 * 64 + ch] + a1 * W0[1 * 64 + ch] + a2 * W0[2 * 64 + ch] + b[ch];
    float sc = g[ch] * rsqrtf(rv[ch] + BN_EPS);
    v = (v - rm[ch]) * sc + beta[ch];
    v = fmaxf(v, 0.0f);
    unsigned short hi = f2bf(v);
    Hhi[(size_t)row * HLD + ch] = hi;
    Hlo[(size_t)row * HLD + ch] = f2bf(v - bf2f(hi));
}

// ---------------- fp16-table gather + BN + ReLU -> hi/lo H slice ----------------
// 16 edges per main iteration -> 8 row-loads in flight per lane.

__global__ __launch_bounds__(256) void gather_bn_relu(
        const __half2* __restrict__ tab2,
        const int* __restrict__ rowptr,
        const unsigned short* __restrict__ esrc16,
        const float* __restrict__ dinv,
        const float* __restrict__ b, const float* __restrict__ g,
        const float* __restrict__ beta, const float* __restrict__ rm,
        const float* __restrict__ rv,
        unsigned short* __restrict__ Hhi, unsigned short* __restrict__ Hlo, int cbase) {
    const int wid = (blockIdx.x * 256 + threadIdx.x) >> 6;
    const int lane = threadIdx.x & 63;
    const int c2 = lane & 31;
    const int grp = lane >> 5;
    if (wid >= NN) return;
    const int beg = rowptr[wid], end = rowptr[wid + 1];
    float a0 = 0.0f, a1 = 0.0f;
    int e = beg + grp;
    for (; e + 14 < end; e += 16) {
        int s0 = esrc16[e],      s1 = esrc16[e + 2],  s2 = esrc16[e + 4],  s3 = esrc16[e + 6];
        int s4 = esrc16[e + 8],  s5 = esrc16[e + 10], s6 = esrc16[e + 12], s7 = esrc16[e + 14];
        float2 f0 = __half22float2(tab2[(size_t)s0 * 32 + c2]);
        float2 f1 = __half22float2(tab2[(size_t)s1 * 32 + c2]);
        float2 f2 = __half22float2(tab2[(size_t)s2 * 32 + c2]);
        float2 f3 = __half22float2(tab2[(size_t)s3 * 32 + c2]);
        float2 f4 = __half22float2(tab2[(size_t)s4 * 32 + c2]);
        float2 f5 = __half22float2(tab2[(size_t)s5 * 32 + c2]);
        float2 f6 = __half22float2(tab2[(size_t)s6 * 32 + c2]);
        float2 f7 = __half22float2(tab2[(size_t)s7 * 32 + c2]);
        a0 += ((f0.x + f1.x) + (f2.x + f3.x)) + ((f4.x + f5.x) + (f6.x + f7.x));
        a1 += ((f0.y + f1.y) + (f2.y + f3.y)) + ((f4.y + f5.y) + (f6.y + f7.y));
    }
    for (; e + 6 < end; e += 8) {
        int s0 = esrc16[e], s1 = esrc16[e + 2], s2 = esrc16[e + 4], s3 = esrc16[e + 6];
        float2 f0 = __half22float2(tab2[(size_t)s0 * 32 + c2]);
        float2 f1 = __half22float2(tab2[(size_t)s1 * 32 + c2]);
        float2 f2 = __half22float2(tab2[(size_t)s2 * 32 + c2]);
        float2 f3 = __half22float2(tab2[(size_t)s3 * 32 + c2]);
        a0 += (f0.x + f1.x) + (f2.x + f3.x);
        a1 += (f0.y + f1.y) + (f2.y + f3.y);
    }
    for (; e < end; e += 2) {
        float2 f = __half22float2(tab2[(size_t)esrc16[e] * 32 + c2]);
        a0 += f.x;
        a1 += f.y;
    }
    a0 += __shfl_xor(a0, 32, 64);
    a1 += __shfl_xor(a1, 32, 64);
    float2 fs = __half22float2(tab2[(size_t)wid * 32 + c2]);  // self-loop
    a0 += fs.x;
    a1 += fs.y;
    const float di = dinv[wid];
    a0 *= di;
    a1 *= di;
    const int ch0 = 2 * c2, ch1 = 2 * c2 + 1;
    float v0 = (a0 + b[ch0] - rm[ch0]) * (g[ch0] * rsqrtf(rv[ch0] + BN_EPS)) + beta[ch0];
    float v1 = (a1 + b[ch1] - rm[ch1]) * (g[ch1] * rsqrtf(rv[ch1] + BN_EPS)) + beta[ch1];
    v0 = fmaxf(v0, 0.0f);
    v1 = fmaxf(v1, 0.0f);
    if (grp == 0) {
        unsigned short h0 = f2bf(v0), h1 = f2bf(v1);
        unsigned short l0 = f2bf(v0 - bf2f(h0)), l1 = f2bf(v1 - bf2f(h1));
        size_t o = (size_t)wid * HLD + cbase + ch0;
        *reinterpret_cast<unsigned int*>(&Hhi[o]) = (unsigned int)h0 | ((unsigned int)h1 << 16);
        *reinterpret_cast<unsigned int*>(&Hlo[o]) = (unsigned int)l0 | ((unsigned int)l1 << 16);
    }
}

// ---------------- decoder (counts via binary search on sorted batch) ----------------

__global__ __launch_bounds__(256) void dec_kernel(
        const float* __restrict__ gfeat_part, const int* __restrict__ batch,
        const float* __restrict__ w0, const float* __restrict__ b0,
        const float* __restrict__ w1, const float* __restrict__ b1,
        float* __restrict__ out) {
    __shared__ float mg[NG][64];
    __shared__ float mc[NG];
    __shared__ float t1[NG][32];
    const int tid = threadIdx.x;
    for (int idx = tid; idx < NG * 64; idx += 256) {
        float s = 0.0f;
#pragma unroll
        for (int p = 0; p < NPART; p++) s += gfeat_part[p * NG * 64 + idx];
        mg[idx >> 6][idx & 63] = s;
    }
    if (tid < NG) {
        int lo = 0, hi = NN;
        while (lo < hi) { int m = (lo + hi) >> 1; if (batch[m] < tid) lo = m + 1; else hi = m; }
        int s0 = lo;
        lo = 0; hi = NN;
        while (lo < hi) { int m = (lo + hi) >> 1; if (batch[m] < tid + 1) lo = m + 1; else hi = m; }
        mc[tid] = (float)(lo - s0);
    }
    __syncthreads();
    const int g = tid >> 5, c = tid & 31;
    float inv = 1.0f / fmaxf(mc[g], 1.0f);
    float acc = b0[c];
    for (int k = 0; k < 64; k++)
        acc = fmaf(mg[g][k] * inv, w0[k * 32 + c], acc);
    t1[g][c] = fmaxf(acc, 0.0f);
    __syncthreads();
    if (tid < NG) {
        float o = b1[0];
        for (int c2 = 0; c2 < 32; c2++) o = fmaf(t1[tid][c2], w1[c2], o);
        out[tid] = o;
    }
}

// ---------------- launch ----------------

extern "C" void kernel_launch(void* const* d_in, const int* in_sizes, int n_in,
                              void* d_out, int out_size, void* d_ws, size_t ws_size,
                              hipStream_t stream) {
    const float* x      = (const float*)d_in[0];
    const int*   ei     = (const int*)d_in[1];
    const int*   batch  = (const int*)d_in[2];
    const float* W0     = (const float*)d_in[3];
    const float* b0     = (const float*)d_in[4];
    const float* g0     = (const float*)d_in[5];
    const float* beta0  = (const float*)d_in[6];
    const float* rm0    = (const float*)d_in[7];
    const float* rv0    = (const float*)d_in[8];
    const float* W1     = (const float*)d_in[9];
    const float* b1     = (const float*)d_in[10];
    const float* g1     = (const float*)d_in[11];
    const float* beta1  = (const float*)d_in[12];
    const float* rm1    = (const float*)d_in[13];
    const float* rv1    = (const float*)d_in[14];
    const float* W2     = (const float*)d_in[15];
    const float* b2     = (const float*)d_in[16];
    const float* g2     = (const float*)d_in[17];
    const float* beta2  = (const float*)d_in[18];
    const float* rm2    = (const float*)d_in[19];
    const float* rv2    = (const float*)d_in[20];
    const float* enc_w0 = (const float*)d_in[21];
    const float* enc_b0 = (const float*)d_in[22];
    const float* enc_w1 = (const float*)d_in[23];
    const float* enc_b1 = (const float*)d_in[24];
    const float* dec_w0 = (const float*)d_in[25];
    const float* dec_b0 = (const float*)d_in[26];
    const float* dec_w1 = (const float*)d_in[27];
    const float* dec_b1 = (const float*)d_in[28];

    const int* esrc = ei;
    const int* edst = ei + NE;

    char* wsb = (char*)d_ws;
    unsigned short* Hhi = (unsigned short*)wsb;                       // [NN*192]
    unsigned short* Hlo = Hhi + (size_t)NN * HLD;                     // [NN*192]
    int*   degi   = (int*)(Hlo + (size_t)NN * HLD);                   // [NN]
    int*   rowptr = degi + NN;                                        // [NN+1]
    int*   cursor = rowptr + NN + 1;                                  // [NN]
    unsigned short* esrc16 = (unsigned short*)(cursor + NN);          // [NE] u16
    __half* tabh  = (__half*)(esrc16 + NE);                           // [NN*64] fp16
    float* dinv   = (float*)(tabh + (size_t)NN * 64);                 // [NN]
    float* xs     = dinv + NN;                                        // [NN*3]
    float* ax     = xs + (size_t)NN * 3;                              // [NN*3]
    float* gfeat_part = ax + (size_t)NN * 3;                          // [8*8*64]
    int*   bsum   = (int*)(gfeat_part + NPART * NG * 64);             // [NBLK]
    unsigned short* wp = (unsigned short*)(bsum + NBLK);
    unsigned short* Wp1h = wp;              unsigned short* Wp1l = Wp1h + 64 * 64;
    unsigned short* Wp2h = Wp1l + 64 * 64;  unsigned short* Wp2l = Wp2h + 128 * 64;
    unsigned short* We0h = Wp2l + 128 * 64; unsigned short* We0l = We0h + 192 * 128;
    unsigned short* We1h = We0l + 192 * 128;unsigned short* We1l = We1h + 128 * 64;

    hipMemsetAsync(degi, 0, NN * sizeof(int), stream);

    // CSR build
    count_deg<<<(NE / 4 + 255) / 256, 256, 0, stream>>>((const int4*)edst, degi);
    scan_partial<<<NBLK, 256, 0, stream>>>(degi, x, rowptr, bsum, dinv, xs);
    scan_bsums<<<1, 256, 0, stream>>>(bsum);
    scan_finalize<<<NBLK, 256, 0, stream>>>(bsum, rowptr, cursor);
    fill_csr<<<(NE + 255) / 256, 256, 0, stream>>>(esrc, edst, cursor, esrc16);

    pack_all<<<(45056 + 255) / 256, 256, 0, stream>>>(W1, W2, enc_w0, enc_w1,
                                                      Wp1h, Wp1l, Wp2h, Wp2l,
                                                      We0h, We0l, We1h, We1l, gfeat_part);

    const int GRID_MFMA = (NN + 63) / 64;
    const int GRID_64   = (NN * 64 + 255) / 256;

    // ---- layer 0 ----
    agg_x3<<<NBLK, 256, 0, stream>>>(xs, rowptr, esrc16, dinv, ax);
    l0_bn_relu<<<GRID_64, 256, 0, stream>>>(ax, W0, b0, g0, beta0, rm0, rv0, Hhi, Hlo);

    // ---- layer 1 ----
    mfma_tab<64><<<GRID_MFMA, 256, 0, stream>>>(Hhi, Hlo, HLD, Wp1h, Wp1l, dinv, tabh);
    gather_bn_relu<<<GRID_64, 256, 0, stream>>>((const __half2*)tabh, rowptr, esrc16, dinv,
                                                b1, g1, beta1, rm1, rv1, Hhi, Hlo, 64);

    // ---- layer 2 ----
    mfma_tab<128><<<GRID_MFMA, 256, 0, stream>>>(Hhi, Hlo, HLD, Wp2h, Wp2l, dinv, tabh);
    gather_bn_relu<<<GRID_64, 256, 0, stream>>>((const __half2*)tabh, rowptr, esrc16, dinv,
                                                b2, g2, beta2, rm2, rv2, Hhi, Hlo, 128);

    // ---- fused encoder + pooling ----
    enc_fused<<<GRID_MFMA, 256, 0, stream>>>(Hhi, Hlo, We0h, We0l, enc_b0,
                                             We1h, We1l, enc_b1, batch, gfeat_part);

    // ---- decode ----
    dec_kernel<<<1, 256, 0, stream>>>(gfeat_part, batch, dec_w0, dec_b0, dec_w1, dec_b1, (float*)d_out);
}

// Round 15
// 230.531 us; speedup vs baseline: 1.1829x; 1.0229x over previous
//
#include <hip/hip_runtime.h>
#include <hip/hip_fp16.h>

#define NN 50000
#define NE 800000
#define NG 8
#define BN_EPS 1e-5f
#define NBLK ((NN + 255) / 256)
#define NPART 8
#define HLD 192   // dedup'd H row width: [c0|c1|c2]

typedef __attribute__((ext_vector_type(8))) short bf16x8;
typedef __attribute__((ext_vector_type(4))) float f32x4;

static __device__ __forceinline__ unsigned short f2bf(float f) {
    unsigned int u = __float_as_uint(f);
    unsigned int r = (u + 0x7FFFu + ((u >> 16) & 1u)) >> 16;   // RNE
    return (unsigned short)r;
}
static __device__ __forceinline__ float bf2f(unsigned short h) {
    return __uint_as_float((unsigned int)h << 16);
}

// ---------------- fused W pack + degi/gfeat zeroing (runs FIRST) ----------------

static __device__ __forceinline__ void pack_one(const float* W, int NOUT, int li,
                                                float v_override, bool use_override,
                                                unsigned short* ph, unsigned short* pl) {
    int j = li & 7;
    int lane = (li >> 3) & 63;
    int rest = li >> 9;
    int NF = NOUT >> 4;
    int f = rest % NF, ks = rest / NF;
    int k = ks * 32 + (lane >> 4) * 8 + j;
    int col = f * 16 + (lane & 15);
    float v = use_override ? v_override : W[k * NOUT + col];
    unsigned short hi = f2bf(v);
    ph[li] = hi;
    pl[li] = f2bf(v - bf2f(hi));
}

__global__ __launch_bounds__(256) void pack_all(
        const float* __restrict__ W1, const float* __restrict__ W2,
        const float* __restrict__ We0, const float* __restrict__ We1,
        unsigned short* __restrict__ Wp1h, unsigned short* __restrict__ Wp1l,
        unsigned short* __restrict__ Wp2h, unsigned short* __restrict__ Wp2l,
        unsigned short* __restrict__ We0h, unsigned short* __restrict__ We0l,
        unsigned short* __restrict__ We1h, unsigned short* __restrict__ We1l,
        int* __restrict__ degi, float* __restrict__ gfeat_part) {
    int idx = blockIdx.x * 256 + threadIdx.x;
    if (idx < NN) degi[idx] = 0;
    if (idx < NPART * NG * 64) gfeat_part[idx] = 0.0f;
    if (idx < 4096) {
        pack_one(W1, 64, idx, 0.f, false, Wp1h, Wp1l);
    } else if (idx < 12288) {
        pack_one(W2, 64, idx - 4096, 0.f, false, Wp2h, Wp2l);
    } else if (idx < 36864) {
        int li = idx - 12288;
        int j = li & 7;
        int lane = (li >> 3) & 63;
        int rest = li >> 9;
        int f = rest % 8, ks = rest / 8;
        int k = ks * 32 + (lane >> 4) * 8 + j;
        int col = f * 16 + (lane & 15);
        float v = (k < 64) ? (We0[k * 128 + col] + We0[(k + 64) * 128 + col])
                           : We0[(k + 64) * 128 + col];
        pack_one(nullptr, 128, li, v, true, We0h, We0l);
    } else if (idx < 45056) {
        pack_one(We1, 64, idx - 36864, 0.f, false, We1h, We1l);
    }
}

// ---------------- CSR build ----------------

__global__ __launch_bounds__(256) void count_deg(const int4* __restrict__ dst4,
                                                 int* __restrict__ degi) {
    int t = blockIdx.x * 256 + threadIdx.x;
    if (t < NE / 4) {
        int4 d = dst4[t];
        atomicAdd(&degi[d.x], 1);
        atomicAdd(&degi[d.y], 1);
        atomicAdd(&degi[d.z], 1);
        atomicAdd(&degi[d.w], 1);
    }
}

__global__ __launch_bounds__(256) void scan_partial(const int* __restrict__ degi,
                                                    const float* __restrict__ x,
                                                    int* __restrict__ rowptr,
                                                    int* __restrict__ bsum,
                                                    float* __restrict__ dinv,
                                                    float* __restrict__ xs) {
    __shared__ int sh[256];
    const int tid = threadIdx.x;
    const int i = blockIdx.x * 256 + tid;
    int v = (i < NN) ? degi[i] : 0;
    if (i < NN) {
        float di = rsqrtf((float)(v + 1));
        dinv[i] = di;
        xs[i * 3 + 0] = x[i * 3 + 0] * di;
        xs[i * 3 + 1] = x[i * 3 + 1] * di;
        xs[i * 3 + 2] = x[i * 3 + 2] * di;
    }
    sh[tid] = v;
    __syncthreads();
#pragma unroll
    for (int off = 1; off < 256; off <<= 1) {
        int t = (tid >= off) ? sh[tid - off] : 0;
        __syncthreads();
        sh[tid] += t;
        __syncthreads();
    }
    if (i < NN) rowptr[i] = sh[tid] - v;
    if (tid == 255) bsum[blockIdx.x] = sh[255];
}

// scan of block sums fused into finalize: every block redundantly scans the
// 196-entry bsum array in LDS (trivial) and applies its own exclusive base.
__global__ __launch_bounds__(256) void scan_finalize(const int* __restrict__ bsum,
                                                     int* __restrict__ rowptr,
                                                     int* __restrict__ cursor) {
    __shared__ int sh[256];
    const int tid = threadIdx.x;
    int v = (tid < NBLK) ? bsum[tid] : 0;
    sh[tid] = v;
    __syncthreads();
#pragma unroll
    for (int off = 1; off < 256; off <<= 1) {
        int t = (tid >= off) ? sh[tid - off] : 0;
        __syncthreads();
        sh[tid] += t;
        __syncthreads();
    }
    const int base = (blockIdx.x == 0) ? 0 : sh[blockIdx.x - 1];
    const int i = blockIdx.x * 256 + tid;
    if (i < NN) {
        int r = rowptr[i] + base;
        rowptr[i] = r;
        cursor[i] = r;
    }
    if (i == 0) rowptr[NN] = NE;
}

__global__ __launch_bounds__(256) void fill_csr(const int* __restrict__ src,
                                                const int* __restrict__ dst,
                                                int* __restrict__ cursor,
                                                unsigned short* __restrict__ esrc16) {
    int e = blockIdx.x * 256 + threadIdx.x;
    if (e < NE) {
        int s = src[e], d = dst[e];
        int p = atomicAdd(&cursor[d], 1);
        esrc16[p] = (unsigned short)s;
    }
}

// ---------------- fused layer 0: wave-per-node aggregate + dense + BN + ReLU ----------------
// 64 lanes split the edge loop, butterfly-reduce a0..a2, lane=channel for the dense part.

__global__ __launch_bounds__(256) void agg_l0(
        const float* __restrict__ xs,
        const int* __restrict__ rowptr,
        const unsigned short* __restrict__ esrc16,
        const float* __restrict__ dinv,
        const float* __restrict__ W0, const float* __restrict__ b,
        const float* __restrict__ g, const float* __restrict__ beta,
        const float* __restrict__ rm, const float* __restrict__ rv,
        unsigned short* __restrict__ Hhi, unsigned short* __restrict__ Hlo) {
    const int wid = (blockIdx.x * 256 + threadIdx.x) >> 6;
    const int lane = threadIdx.x & 63;
    if (wid >= NN) return;
    const int beg = rowptr[wid], end = rowptr[wid + 1];
    float a0 = 0.0f, a1 = 0.0f, a2 = 0.0f;
    for (int e = beg + lane; e < end; e += 64) {
        int s = esrc16[e];
        a0 += xs[s * 3 + 0];
        a1 += xs[s * 3 + 1];
        a2 += xs[s * 3 + 2];
    }
#pragma unroll
    for (int off = 32; off >= 1; off >>= 1) {
        a0 += __shfl_xor(a0, off, 64);
        a1 += __shfl_xor(a1, off, 64);
        a2 += __shfl_xor(a2, off, 64);
    }
    a0 += xs[wid * 3 + 0];   // self-loop (pre-scaled)
    a1 += xs[wid * 3 + 1];
    a2 += xs[wid * 3 + 2];
    const float di = dinv[wid];
    a0 *= di; a1 *= di; a2 *= di;
    const int ch = lane;
    float v = a0 * W0[ch] + a1 * W0[64 + ch] + a2 * W0[128 + ch] + b[ch];
    float sc = g[ch] * rsqrtf(rv[ch] + BN_EPS);
    v = (v - rm[ch]) * sc + beta[ch];
    v = fmaxf(v, 0.0f);
    unsigned short hi = f2bf(v);
    Hhi[(size_t)wid * HLD + ch] = hi;
    Hlo[(size_t)wid * HLD + ch] = f2bf(v - bf2f(hi));
}

// ---------------- split-bf16 MFMA GEMM -> fp16 gather table ----------------

template<int K>
__global__ __launch_bounds__(256, 2) void mfma_tab(
        const unsigned short* __restrict__ Ahi,
        const unsigned short* __restrict__ Alo, int lda,
        const unsigned short* __restrict__ Bph,
        const unsigned short* __restrict__ Bpl,
        const float* __restrict__ dinv,
        __half* __restrict__ outH) {
    constexpr int KS = K / 32;
    const int wave = threadIdx.x >> 6;
    const int lane = threadIdx.x & 63;
    const int rbase = blockIdx.x * 64 + wave * 16;
    int arow = rbase + (lane & 15);
    if (arow >= NN) arow = NN - 1;
    const int kbase = (lane >> 4) * 8;

    bf16x8 bh[KS][4], bl[KS][4];
#pragma unroll
    for (int ks = 0; ks < KS; ks++)
#pragma unroll
        for (int f = 0; f < 4; f++) {
            bh[ks][f] = *reinterpret_cast<const bf16x8*>(Bph + (size_t)((ks * 4 + f) * 64 + lane) * 8);
            bl[ks][f] = *reinterpret_cast<const bf16x8*>(Bpl + (size_t)((ks * 4 + f) * 64 + lane) * 8);
        }

    const unsigned short* pa_hi = Ahi + (size_t)arow * lda + kbase;
    const unsigned short* pa_lo = Alo + (size_t)arow * lda + kbase;
    bf16x8 ah[KS], al[KS];
#pragma unroll
    for (int ks = 0; ks < KS; ks++) {
        ah[ks] = *reinterpret_cast<const bf16x8*>(pa_hi + ks * 32);
        al[ks] = *reinterpret_cast<const bf16x8*>(pa_lo + ks * 32);
    }

    f32x4 acc[4];
#pragma unroll
    for (int f = 0; f < 4; f++) acc[f] = (f32x4){0.f, 0.f, 0.f, 0.f};

#pragma unroll
    for (int ks = 0; ks < KS; ks++)
#pragma unroll
        for (int f = 0; f < 4; f++) {
            acc[f] = __builtin_amdgcn_mfma_f32_16x16x32_bf16(ah[ks], bh[ks][f], acc[f], 0, 0, 0);
            acc[f] = __builtin_amdgcn_mfma_f32_16x16x32_bf16(ah[ks], bl[ks][f], acc[f], 0, 0, 0);
            acc[f] = __builtin_amdgcn_mfma_f32_16x16x32_bf16(al[ks], bh[ks][f], acc[f], 0, 0, 0);
        }

    const int drow0 = rbase + (lane >> 4) * 4;
    const int dcol = lane & 15;
#pragma unroll
    for (int f = 0; f < 4; f++) {
#pragma unroll
        for (int r = 0; r < 4; r++) {
            int row = drow0 + r;
            if (row < NN)
                outH[(size_t)row * 64 + f * 16 + dcol] = __float2half(acc[f][r] * dinv[row]);
        }
    }
}

// ---------------- fused encoder (enc0 -> LDS -> enc1) + pooling ----------------

__global__ __launch_bounds__(256, 2) void enc_fused(
        const unsigned short* __restrict__ Hhi,
        const unsigned short* __restrict__ Hlo,
        const unsigned short* __restrict__ We0h, const unsigned short* __restrict__ We0l,
        const float* __restrict__ b0,
        const unsigned short* __restrict__ We1h, const unsigned short* __restrict__ We1l,
        const float* __restrict__ b1,
        const int* __restrict__ batch,
        float* __restrict__ gfeat_part) {
    __shared__ float ldsT[4][16][133];
    __shared__ float poolw[4][64];
    __shared__ float pool[NG][64];
    const int tid = threadIdx.x;
    const int wave = tid >> 6;
    const int lane = tid & 63;
    const int rbase = blockIdx.x * 64 + wave * 16;

    // ---- stage A: T = relu(H @ We0 + b0), K=192, NF=8, B double-buffered ----
    int arow = rbase + (lane & 15);
    if (arow >= NN) arow = NN - 1;
    const int kbase = (lane >> 4) * 8;
    f32x4 acc[8];
#pragma unroll
    for (int f = 0; f < 8; f++) acc[f] = (f32x4){0.f, 0.f, 0.f, 0.f};

    const unsigned short* pa_hi = Hhi + (size_t)arow * HLD + kbase;
    const unsigned short* pa_lo = Hlo + (size_t)arow * HLD + kbase;

    bf16x8 cbh[8], cbl[8], nbh[8], nbl[8];
#pragma unroll
    for (int f = 0; f < 8; f++) {
        cbh[f] = *reinterpret_cast<const bf16x8*>(We0h + (size_t)(f * 64 + lane) * 8);
        cbl[f] = *reinterpret_cast<const bf16x8*>(We0l + (size_t)(f * 64 + lane) * 8);
    }
#pragma unroll
    for (int ks = 0; ks < 6; ks++) {
        if (ks < 5) {
#pragma unroll
            for (int f = 0; f < 8; f++) {
                nbh[f] = *reinterpret_cast<const bf16x8*>(We0h + (size_t)(((ks + 1) * 8 + f) * 64 + lane) * 8);
                nbl[f] = *reinterpret_cast<const bf16x8*>(We0l + (size_t)(((ks + 1) * 8 + f) * 64 + lane) * 8);
            }
        }
        bf16x8 ah = *reinterpret_cast<const bf16x8*>(pa_hi + ks * 32);
        bf16x8 al = *reinterpret_cast<const bf16x8*>(pa_lo + ks * 32);
#pragma unroll
        for (int f = 0; f < 8; f++) {
            acc[f] = __builtin_amdgcn_mfma_f32_16x16x32_bf16(ah, cbh[f], acc[f], 0, 0, 0);
            acc[f] = __builtin_amdgcn_mfma_f32_16x16x32_bf16(ah, cbl[f], acc[f], 0, 0, 0);
            acc[f] = __builtin_amdgcn_mfma_f32_16x16x32_bf16(al, cbh[f], acc[f], 0, 0, 0);
        }
        if (ks < 5) {
#pragma unroll
            for (int f = 0; f < 8; f++) { cbh[f] = nbh[f]; cbl[f] = nbl[f]; }
        }
    }

    const int lrow0 = (lane >> 4) * 4;
    const int dcol = lane & 15;
#pragma unroll
    for (int f = 0; f < 8; f++) {
#pragma unroll
        for (int r = 0; r < 4; r++) {
            float v = fmaxf(acc[f][r] + b0[f * 16 + dcol], 0.0f);
            ldsT[wave][lrow0 + r][f * 16 + dcol] = v;
        }
    }
    __syncthreads();

    // ---- stage B: out = relu(T @ We1 + b1), K=128, NF=4; We1 hoisted ----
    bf16x8 wbh[4][4], wbl[4][4];
#pragma unroll
    for (int ks = 0; ks < 4; ks++)
#pragma unroll
        for (int f = 0; f < 4; f++) {
            wbh[ks][f] = *reinterpret_cast<const bf16x8*>(We1h + (size_t)((ks * 4 + f) * 64 + lane) * 8);
            wbl[ks][f] = *reinterpret_cast<const bf16x8*>(We1l + (size_t)((ks * 4 + f) * 64 + lane) * 8);
        }

    f32x4 acc2[4];
#pragma unroll
    for (int f = 0; f < 4; f++) acc2[f] = (f32x4){0.f, 0.f, 0.f, 0.f};

    const int trow = lane & 15;
#pragma unroll
    for (int ks = 0; ks < 4; ks++) {
        bf16x8 ah, al;
#pragma unroll
        for (int j = 0; j < 8; j++) {
            float tv = ldsT[wave][trow][ks * 32 + (lane >> 4) * 8 + j];
            unsigned short hi = f2bf(tv);
            ah[j] = (short)hi;
            al[j] = (short)f2bf(tv - bf2f(hi));
        }
#pragma unroll
        for (int f = 0; f < 4; f++) {
            acc2[f] = __builtin_amdgcn_mfma_f32_16x16x32_bf16(ah, wbh[ks][f], acc2[f], 0, 0, 0);
            acc2[f] = __builtin_amdgcn_mfma_f32_16x16x32_bf16(ah, wbl[ks][f], acc2[f], 0, 0, 0);
            acc2[f] = __builtin_amdgcn_mfma_f32_16x16x32_bf16(al, wbh[ks][f], acc2[f], 0, 0, 0);
        }
    }

    // ---- epilogue: bias+relu, pool ----
    float vout[4][4];
#pragma unroll
    for (int f = 0; f < 4; f++)
#pragma unroll
        for (int r = 0; r < 4; r++) {
            int row = rbase + lrow0 + r;
            vout[f][r] = (row < NN) ? fmaxf(acc2[f][r] + b1[f * 16 + dcol], 0.0f) : 0.0f;
        }

    const int blk_row0 = blockIdx.x * 64;
    const int blk_rowN = min(blk_row0 + 63, NN - 1);
    const int g0 = batch[blk_row0];
    const int p = blockIdx.x & (NPART - 1);

    if (g0 == batch[blk_rowN]) {
#pragma unroll
        for (int f = 0; f < 4; f++) {
            float s = (vout[f][0] + vout[f][1]) + (vout[f][2] + vout[f][3]);
            s += __shfl_xor(s, 16, 64);
            s += __shfl_xor(s, 32, 64);
            if ((lane >> 4) == 0) poolw[wave][f * 16 + dcol] = s;
        }
        __syncthreads();
        if (tid < 64) {
            float s = (poolw[0][tid] + poolw[1][tid]) + (poolw[2][tid] + poolw[3][tid]);
            atomicAdd(&gfeat_part[(p * NG + g0) * 64 + tid], s);
        }
    } else {
        for (int i = tid; i < NG * 64; i += 256) ((float*)pool)[i] = 0.0f;
        __syncthreads();
#pragma unroll
        for (int r = 0; r < 4; r++) {
            int row = rbase + lrow0 + r;
            if (row < NN) {
                int g = batch[row];
#pragma unroll
                for (int f = 0; f < 4; f++)
                    atomicAdd(&pool[g][f * 16 + dcol], vout[f][r]);
            }
        }
        __syncthreads();
        for (int i = tid; i < NG * 64; i += 256) {
            float s = ((float*)pool)[i];
            if (s != 0.0f) atomicAdd(&gfeat_part[p * NG * 64 + i], s);
        }
    }
}

// ---------------- fp16-table gather + BN + ReLU -> hi/lo H slice ----------------

__global__ __launch_bounds__(256) void gather_bn_relu(
        const __half2* __restrict__ tab2,
        const int* __restrict__ rowptr,
        const unsigned short* __restrict__ esrc16,
        const float* __restrict__ dinv,
        const float* __restrict__ b, const float* __restrict__ g,
        const float* __restrict__ beta, const float* __restrict__ rm,
        const float* __restrict__ rv,
        unsigned short* __restrict__ Hhi, unsigned short* __restrict__ Hlo, int cbase) {
    const int wid = (blockIdx.x * 256 + threadIdx.x) >> 6;
    const int lane = threadIdx.x & 63;
    const int c2 = lane & 31;
    const int grp = lane >> 5;
    if (wid >= NN) return;
    const int beg = rowptr[wid], end = rowptr[wid + 1];
    float a0 = 0.0f, a1 = 0.0f;
    int e = beg + grp;
    for (; e + 14 < end; e += 16) {
        int s0 = esrc16[e],      s1 = esrc16[e + 2],  s2 = esrc16[e + 4],  s3 = esrc16[e + 6];
        int s4 = esrc16[e + 8],  s5 = esrc16[e + 10], s6 = esrc16[e + 12], s7 = esrc16[e + 14];
        float2 f0 = __half22float2(tab2[(size_t)s0 * 32 + c2]);
        float2 f1 = __half22float2(tab2[(size_t)s1 * 32 + c2]);
        float2 f2 = __half22float2(tab2[(size_t)s2 * 32 + c2]);
        float2 f3 = __half22float2(tab2[(size_t)s3 * 32 + c2]);
        float2 f4 = __half22float2(tab2[(size_t)s4 * 32 + c2]);
        float2 f5 = __half22float2(tab2[(size_t)s5 * 32 + c2]);
        float2 f6 = __half22float2(tab2[(size_t)s6 * 32 + c2]);
        float2 f7 = __half22float2(tab2[(size_t)s7 * 32 + c2]);
        a0 += ((f0.x + f1.x) + (f2.x + f3.x)) + ((f4.x + f5.x) + (f6.x + f7.x));
        a1 += ((f0.y + f1.y) + (f2.y + f3.y)) + ((f4.y + f5.y) + (f6.y + f7.y));
    }
    for (; e + 6 < end; e += 8) {
        int s0 = esrc16[e], s1 = esrc16[e + 2], s2 = esrc16[e + 4], s3 = esrc16[e + 6];
        float2 f0 = __half22float2(tab2[(size_t)s0 * 32 + c2]);
        float2 f1 = __half22float2(tab2[(size_t)s1 * 32 + c2]);
        float2 f2 = __half22float2(tab2[(size_t)s2 * 32 + c2]);
        float2 f3 = __half22float2(tab2[(size_t)s3 * 32 + c2]);
        a0 += (f0.x + f1.x) + (f2.x + f3.x);
        a1 += (f0.y + f1.y) + (f2.y + f3.y);
    }
    for (; e < end; e += 2) {
        float2 f = __half22float2(tab2[(size_t)esrc16[e] * 32 + c2]);
        a0 += f.x;
        a1 += f.y;
    }
    a0 += __shfl_xor(a0, 32, 64);
    a1 += __shfl_xor(a1, 32, 64);
    float2 fs = __half22float2(tab2[(size_t)wid * 32 + c2]);  // self-loop
    a0 += fs.x;
    a1 += fs.y;
    const float di = dinv[wid];
    a0 *= di;
    a1 *= di;
    const int ch0 = 2 * c2, ch1 = 2 * c2 + 1;
    float v0 = (a0 + b[ch0] - rm[ch0]) * (g[ch0] * rsqrtf(rv[ch0] + BN_EPS)) + beta[ch0];
    float v1 = (a1 + b[ch1] - rm[ch1]) * (g[ch1] * rsqrtf(rv[ch1] + BN_EPS)) + beta[ch1];
    v0 = fmaxf(v0, 0.0f);
    v1 = fmaxf(v1, 0.0f);
    if (grp == 0) {
        unsigned short h0 = f2bf(v0), h1 = f2bf(v1);
        unsigned short l0 = f2bf(v0 - bf2f(h0)), l1 = f2bf(v1 - bf2f(h1));
        size_t o = (size_t)wid * HLD + cbase + ch0;
        *reinterpret_cast<unsigned int*>(&Hhi[o]) = (unsigned int)h0 | ((unsigned int)h1 << 16);
        *reinterpret_cast<unsigned int*>(&Hlo[o]) = (unsigned int)l0 | ((unsigned int)l1 << 16);
    }
}

// ---------------- decoder (counts via binary search on sorted batch) ----------------

__global__ __launch_bounds__(256) void dec_kernel(
        const float* __restrict__ gfeat_part, const int* __restrict__ batch,
        const float* __restrict__ w0, const float* __restrict__ b0,
        const float* __restrict__ w1, const float* __restrict__ b1,
        float* __restrict__ out) {
    __shared__ float mg[NG][64];
    __shared__ float mc[NG];
    __shared__ float t1[NG][32];
    const int tid = threadIdx.x;
    for (int idx = tid; idx < NG * 64; idx += 256) {
        float s = 0.0f;
#pragma unroll
        for (int p = 0; p < NPART; p++) s += gfeat_part[p * NG * 64 + idx];
        mg[idx >> 6][idx & 63] = s;
    }
    if (tid < NG) {
        int lo = 0, hi = NN;
        while (lo < hi) { int m = (lo + hi) >> 1; if (batch[m] < tid) lo = m + 1; else hi = m; }
        int s0 = lo;
        lo = 0; hi = NN;
        while (lo < hi) { int m = (lo + hi) >> 1; if (batch[m] < tid + 1) lo = m + 1; else hi = m; }
        mc[tid] = (float)(lo - s0);
    }
    __syncthreads();
    const int g = tid >> 5, c = tid & 31;
    float inv = 1.0f / fmaxf(mc[g], 1.0f);
    float acc = b0[c];
    for (int k = 0; k < 64; k++)
        acc = fmaf(mg[g][k] * inv, w0[k * 32 + c], acc);
    t1[g][c] = fmaxf(acc, 0.0f);
    __syncthreads();
    if (tid < NG) {
        float o = b1[0];
        for (int c2 = 0; c2 < 32; c2++) o = fmaf(t1[tid][c2], w1[c2], o);
        out[tid] = o;
    }
}

// ---------------- launch ----------------

extern "C" void kernel_launch(void* const* d_in, const int* in_sizes, int n_in,
                              void* d_out, int out_size, void* d_ws, size_t ws_size,
                              hipStream_t stream) {
    const float* x      = (const float*)d_in[0];
    const int*   ei     = (const int*)d_in[1];
    const int*   batch  = (const int*)d_in[2];
    const float* W0     = (const float*)d_in[3];
    const float* b0     = (const float*)d_in[4];
    const float* g0     = (const float*)d_in[5];
    const float* beta0  = (const float*)d_in[6];
    const float* rm0    = (const float*)d_in[7];
    const float* rv0    = (const float*)d_in[8];
    const float* W1     = (const float*)d_in[9];
    const float* b1     = (const float*)d_in[10];
    const float* g1     = (const float*)d_in[11];
    const float* beta1  = (const float*)d_in[12];
    const float* rm1    = (const float*)d_in[13];
    const float* rv1    = (const float*)d_in[14];
    const float* W2     = (const float*)d_in[15];
    const float* b2     = (const float*)d_in[16];
    const float* g2     = (const float*)d_in[17];
    const float* beta2  = (const float*)d_in[18];
    const float* rm2    = (const float*)d_in[19];
    const float* rv2    = (const float*)d_in[20];
    const float* enc_w0 = (const float*)d_in[21];
    const float* enc_b0 = (const float*)d_in[22];
    const float* enc_w1 = (const float*)d_in[23];
    const float* enc_b1 = (const float*)d_in[24];
    const float* dec_w0 = (const float*)d_in[25];
    const float* dec_b0 = (const float*)d_in[26];
    const float* dec_w1 = (const float*)d_in[27];
    const float* dec_b1 = (const float*)d_in[28];

    const int* esrc = ei;
    const int* edst = ei + NE;

    char* wsb = (char*)d_ws;
    unsigned short* Hhi = (unsigned short*)wsb;                       // [NN*192]
    unsigned short* Hlo = Hhi + (size_t)NN * HLD;                     // [NN*192]
    int*   degi   = (int*)(Hlo + (size_t)NN * HLD);                   // [NN]
    int*   rowptr = degi + NN;                                        // [NN+1]
    int*   cursor = rowptr + NN + 1;                                  // [NN]
    unsigned short* esrc16 = (unsigned short*)(cursor + NN);          // [NE] u16
    __half* tabh  = (__half*)(esrc16 + NE);                           // [NN*64] fp16
    float* dinv   = (float*)(tabh + (size_t)NN * 64);                 // [NN]
    float* xs     = dinv + NN;                                        // [NN*3]
    float* gfeat_part = xs + (size_t)NN * 3;                          // [8*8*64]
    int*   bsum   = (int*)(gfeat_part + NPART * NG * 64);             // [NBLK]
    unsigned short* wp = (unsigned short*)(bsum + NBLK);
    unsigned short* Wp1h = wp;              unsigned short* Wp1l = Wp1h + 64 * 64;
    unsigned short* Wp2h = Wp1l + 64 * 64;  unsigned short* Wp2l = Wp2h + 128 * 64;
    unsigned short* We0h = Wp2l + 128 * 64; unsigned short* We0l = We0h + 192 * 128;
    unsigned short* We1h = We0l + 192 * 128;unsigned short* We1l = We1h + 128 * 64;

    const int GRID_MFMA = (NN + 63) / 64;
    const int GRID_64   = (NN * 64 + 255) / 256;

    // pack weights + zero degi/gfeat (one dispatch, runs first)
    pack_all<<<NBLK, 256, 0, stream>>>(W1, W2, enc_w0, enc_w1,
                                       Wp1h, Wp1l, Wp2h, Wp2l,
                                       We0h, We0l, We1h, We1l, degi, gfeat_part);

    // CSR build
    count_deg<<<(NE / 4 + 255) / 256, 256, 0, stream>>>((const int4*)edst, degi);
    scan_partial<<<NBLK, 256, 0, stream>>>(degi, x, rowptr, bsum, dinv, xs);
    scan_finalize<<<NBLK, 256, 0, stream>>>(bsum, rowptr, cursor);
    fill_csr<<<(NE + 255) / 256, 256, 0, stream>>>(esrc, edst, cursor, esrc16);

    // ---- layer 0 (fused aggregate + dense + BN + ReLU) ----
    agg_l0<<<GRID_64, 256, 0, stream>>>(xs, rowptr, esrc16, dinv,
                                        W0, b0, g0, beta0, rm0, rv0, Hhi, Hlo);

    // ---- layer 1 ----
    mfma_tab<64><<<GRID_MFMA, 256, 0, stream>>>(Hhi, Hlo, HLD, Wp1h, Wp1l, dinv, tabh);
    gather_bn_relu<<<GRID_64, 256, 0, stream>>>((const __half2*)tabh, rowptr, esrc16, dinv,
                                                b1, g1, beta1, rm1, rv1, Hhi, Hlo, 64);

    // ---- layer 2 ----
    mfma_tab<128><<<GRID_MFMA, 256, 0, stream>>>(Hhi, Hlo, HLD, Wp2h, Wp2l, dinv, tabh);
    gather_bn_relu<<<GRID_64, 256, 0, stream>>>((const __half2*)tabh, rowptr, esrc16, dinv,
                                                b2, g2, beta2, rm2, rv2, Hhi, Hlo, 128);

    // ---- fused encoder + pooling ----
    enc_fused<<<GRID_MFMA, 256, 0, stream>>>(Hhi, Hlo, We0h, We0l, enc_b0,
                                             We1h, We1l, enc_b1, batch, gfeat_part);

    // ---- decode ----
    dec_kernel<<<1, 256, 0, stream>>>(gfeat_part, batch, dec_w0, dec_b0, dec_w1, dec_b1, (float*)d_out);
}

// Round 16
// 227.728 us; speedup vs baseline: 1.1975x; 1.0123x over previous
//
#include <hip/hip_runtime.h>
#include <hip/hip_fp16.h>

#define NN 50000
#define NE 800000
#define NG 8
#define BN_EPS 1e-5f
#define NBLK ((NN + 255) / 256)
#define NPART 8
#define HLD 192   // dedup'd H row width: [c0|c1|c2]
#define FC_CHUNK 2048
#define FC_NCHUNK ((NE + FC_CHUNK - 1) / FC_CHUNK)   // 391
#define PART_SZ (NN / 8)                              // 6250 exact

typedef __attribute__((ext_vector_type(8))) short bf16x8;
typedef __attribute__((ext_vector_type(4))) float f32x4;

static __device__ __forceinline__ unsigned short f2bf(float f) {
    unsigned int u = __float_as_uint(f);
    unsigned int r = (u + 0x7FFFu + ((u >> 16) & 1u)) >> 16;   // RNE
    return (unsigned short)r;
}
static __device__ __forceinline__ float bf2f(unsigned short h) {
    return __uint_as_float((unsigned int)h << 16);
}

// ---------------- fused W pack + degi/gfeat zeroing (runs FIRST) ----------------

static __device__ __forceinline__ void pack_one(const float* W, int NOUT, int li,
                                                float v_override, bool use_override,
                                                unsigned short* ph, unsigned short* pl) {
    int j = li & 7;
    int lane = (li >> 3) & 63;
    int rest = li >> 9;
    int NF = NOUT >> 4;
    int f = rest % NF, ks = rest / NF;
    int k = ks * 32 + (lane >> 4) * 8 + j;
    int col = f * 16 + (lane & 15);
    float v = use_override ? v_override : W[k * NOUT + col];
    unsigned short hi = f2bf(v);
    ph[li] = hi;
    pl[li] = f2bf(v - bf2f(hi));
}

__global__ __launch_bounds__(256) void pack_all(
        const float* __restrict__ W1, const float* __restrict__ W2,
        const float* __restrict__ We0, const float* __restrict__ We1,
        unsigned short* __restrict__ Wp1h, unsigned short* __restrict__ Wp1l,
        unsigned short* __restrict__ Wp2h, unsigned short* __restrict__ Wp2l,
        unsigned short* __restrict__ We0h, unsigned short* __restrict__ We0l,
        unsigned short* __restrict__ We1h, unsigned short* __restrict__ We1l,
        int* __restrict__ degi, float* __restrict__ gfeat_part) {
    int idx = blockIdx.x * 256 + threadIdx.x;
    if (idx < NN) degi[idx] = 0;
    if (idx < NPART * NG * 64) gfeat_part[idx] = 0.0f;
    if (idx < 4096) {
        pack_one(W1, 64, idx, 0.f, false, Wp1h, Wp1l);
    } else if (idx < 12288) {
        pack_one(W2, 64, idx - 4096, 0.f, false, Wp2h, Wp2l);
    } else if (idx < 36864) {
        int li = idx - 12288;
        int j = li & 7;
        int lane = (li >> 3) & 63;
        int rest = li >> 9;
        int f = rest % 8, ks = rest / 8;
        int k = ks * 32 + (lane >> 4) * 8 + j;
        int col = f * 16 + (lane & 15);
        float v = (k < 64) ? (We0[k * 128 + col] + We0[(k + 64) * 128 + col])
                           : We0[(k + 64) * 128 + col];
        pack_one(nullptr, 128, li, v, true, We0h, We0l);
    } else if (idx < 45056) {
        pack_one(We1, 64, idx - 36864, 0.f, false, We1h, We1l);
    }
}

// ---------------- CSR build: dst-partitioned (XCD-local scatter) ----------------
// partition = blockIdx&7 owns dst range [p*6250, (p+1)*6250); each block scans
// one 2048-edge chunk. 8x read amplification is L2/L3-served; writes+atomics
// become XCD-local -> full-line coalescing instead of cross-XCD sector bounce.

__global__ __launch_bounds__(256) void count_deg_p(const int* __restrict__ dst,
                                                   int* __restrict__ degi) {
    const int part = blockIdx.x & 7;
    const int chunk = blockIdx.x >> 3;
    const int lo = part * PART_SZ, hi = lo + PART_SZ;
    const int e0 = chunk * FC_CHUNK;
    const int e1 = min(e0 + FC_CHUNK, NE);
    for (int e = e0 + threadIdx.x; e < e1; e += 256) {
        int d = dst[e];
        if (d >= lo && d < hi) atomicAdd(&degi[d], 1);
    }
}

__global__ __launch_bounds__(256) void fill_csr_p(const int* __restrict__ src,
                                                  const int* __restrict__ dst,
                                                  int* __restrict__ cursor,
                                                  unsigned short* __restrict__ esrc16) {
    const int part = blockIdx.x & 7;
    const int chunk = blockIdx.x >> 3;
    const int lo = part * PART_SZ, hi = lo + PART_SZ;
    const int e0 = chunk * FC_CHUNK;
    const int e1 = min(e0 + FC_CHUNK, NE);
    for (int e = e0 + threadIdx.x; e < e1; e += 256) {
        int d = dst[e];
        if (d >= lo && d < hi) {
            int p = atomicAdd(&cursor[d], 1);
            esrc16[p] = (unsigned short)src[e];
        }
    }
}

// ---------------- scan ----------------

__global__ __launch_bounds__(256) void scan_partial(const int* __restrict__ degi,
                                                    const float* __restrict__ x,
                                                    int* __restrict__ rowptr,
                                                    int* __restrict__ bsum,
                                                    float* __restrict__ dinv,
                                                    float* __restrict__ xs) {
    __shared__ int sh[256];
    const int tid = threadIdx.x;
    const int i = blockIdx.x * 256 + tid;
    int v = (i < NN) ? degi[i] : 0;
    if (i < NN) {
        float di = rsqrtf((float)(v + 1));
        dinv[i] = di;
        xs[i * 3 + 0] = x[i * 3 + 0] * di;
        xs[i * 3 + 1] = x[i * 3 + 1] * di;
        xs[i * 3 + 2] = x[i * 3 + 2] * di;
    }
    sh[tid] = v;
    __syncthreads();
#pragma unroll
    for (int off = 1; off < 256; off <<= 1) {
        int t = (tid >= off) ? sh[tid - off] : 0;
        __syncthreads();
        sh[tid] += t;
        __syncthreads();
    }
    if (i < NN) rowptr[i] = sh[tid] - v;
    if (tid == 255) bsum[blockIdx.x] = sh[255];
}

__global__ __launch_bounds__(256) void scan_finalize(const int* __restrict__ bsum,
                                                     int* __restrict__ rowptr,
                                                     int* __restrict__ cursor) {
    __shared__ int sh[256];
    const int tid = threadIdx.x;
    int v = (tid < NBLK) ? bsum[tid] : 0;
    sh[tid] = v;
    __syncthreads();
#pragma unroll
    for (int off = 1; off < 256; off <<= 1) {
        int t = (tid >= off) ? sh[tid - off] : 0;
        __syncthreads();
        sh[tid] += t;
        __syncthreads();
    }
    const int base = (blockIdx.x == 0) ? 0 : sh[blockIdx.x - 1];
    const int i = blockIdx.x * 256 + tid;
    if (i < NN) {
        int r = rowptr[i] + base;
        rowptr[i] = r;
        cursor[i] = r;
    }
    if (i == 0) rowptr[NN] = NE;
}

// ---------------- fused layer 0: wave-per-node aggregate + dense + BN + ReLU ----------------

__global__ __launch_bounds__(256) void agg_l0(
        const float* __restrict__ xs,
        const int* __restrict__ rowptr,
        const unsigned short* __restrict__ esrc16,
        const float* __restrict__ dinv,
        const float* __restrict__ W0, const float* __restrict__ b,
        const float* __restrict__ g, const float* __restrict__ beta,
        const float* __restrict__ rm, const float* __restrict__ rv,
        unsigned short* __restrict__ Hhi, unsigned short* __restrict__ Hlo) {
    const int wid = (blockIdx.x * 256 + threadIdx.x) >> 6;
    const int lane = threadIdx.x & 63;
    if (wid >= NN) return;
    const int beg = rowptr[wid], end = rowptr[wid + 1];
    float a0 = 0.0f, a1 = 0.0f, a2 = 0.0f;
    for (int e = beg + lane; e < end; e += 64) {
        int s = esrc16[e];
        a0 += xs[s * 3 + 0];
        a1 += xs[s * 3 + 1];
        a2 += xs[s * 3 + 2];
    }
#pragma unroll
    for (int off = 32; off >= 1; off >>= 1) {
        a0 += __shfl_xor(a0, off, 64);
        a1 += __shfl_xor(a1, off, 64);
        a2 += __shfl_xor(a2, off, 64);
    }
    a0 += xs[wid * 3 + 0];
    a1 += xs[wid * 3 + 1];
    a2 += xs[wid * 3 + 2];
    const float di = dinv[wid];
    a0 *= di; a1 *= di; a2 *= di;
    const int ch = lane;
    float v = a0 * W0[ch] + a1 * W0[64 + ch] + a2 * W0[128 + ch] + b[ch];
    float sc = g[ch] * rsqrtf(rv[ch] + BN_EPS);
    v = (v - rm[ch]) * sc + beta[ch];
    v = fmaxf(v, 0.0f);
    unsigned short hi = f2bf(v);
    Hhi[(size_t)wid * HLD + ch] = hi;
    Hlo[(size_t)wid * HLD + ch] = f2bf(v - bf2f(hi));
}

// ---------------- split-bf16 MFMA GEMM -> fp16 gather table ----------------

template<int K>
__global__ __launch_bounds__(256, 2) void mfma_tab(
        const unsigned short* __restrict__ Ahi,
        const unsigned short* __restrict__ Alo, int lda,
        const unsigned short* __restrict__ Bph,
        const unsigned short* __restrict__ Bpl,
        const float* __restrict__ dinv,
        __half* __restrict__ outH) {
    constexpr int KS = K / 32;
    const int wave = threadIdx.x >> 6;
    const int lane = threadIdx.x & 63;
    const int rbase = blockIdx.x * 64 + wave * 16;
    int arow = rbase + (lane & 15);
    if (arow >= NN) arow = NN - 1;
    const int kbase = (lane >> 4) * 8;

    bf16x8 bh[KS][4], bl[KS][4];
#pragma unroll
    for (int ks = 0; ks < KS; ks++)
#pragma unroll
        for (int f = 0; f < 4; f++) {
            bh[ks][f] = *reinterpret_cast<const bf16x8*>(Bph + (size_t)((ks * 4 + f) * 64 + lane) * 8);
            bl[ks][f] = *reinterpret_cast<const bf16x8*>(Bpl + (size_t)((ks * 4 + f) * 64 + lane) * 8);
        }

    const unsigned short* pa_hi = Ahi + (size_t)arow * lda + kbase;
    const unsigned short* pa_lo = Alo + (size_t)arow * lda + kbase;
    bf16x8 ah[KS], al[KS];
#pragma unroll
    for (int ks = 0; ks < KS; ks++) {
        ah[ks] = *reinterpret_cast<const bf16x8*>(pa_hi + ks * 32);
        al[ks] = *reinterpret_cast<const bf16x8*>(pa_lo + ks * 32);
    }

    f32x4 acc[4];
#pragma unroll
    for (int f = 0; f < 4; f++) acc[f] = (f32x4){0.f, 0.f, 0.f, 0.f};

#pragma unroll
    for (int ks = 0; ks < KS; ks++)
#pragma unroll
        for (int f = 0; f < 4; f++) {
            acc[f] = __builtin_amdgcn_mfma_f32_16x16x32_bf16(ah[ks], bh[ks][f], acc[f], 0, 0, 0);
            acc[f] = __builtin_amdgcn_mfma_f32_16x16x32_bf16(ah[ks], bl[ks][f], acc[f], 0, 0, 0);
            acc[f] = __builtin_amdgcn_mfma_f32_16x16x32_bf16(al[ks], bh[ks][f], acc[f], 0, 0, 0);
        }

    const int drow0 = rbase + (lane >> 4) * 4;
    const int dcol = lane & 15;
#pragma unroll
    for (int f = 0; f < 4; f++) {
#pragma unroll
        for (int r = 0; r < 4; r++) {
            int row = drow0 + r;
            if (row < NN)
                outH[(size_t)row * 64 + f * 16 + dcol] = __float2half(acc[f][r] * dinv[row]);
        }
    }
}

// ---------------- fused encoder (enc0 -> LDS -> enc1) + pooling ----------------

__global__ __launch_bounds__(256, 2) void enc_fused(
        const unsigned short* __restrict__ Hhi,
        const unsigned short* __restrict__ Hlo,
        const unsigned short* __restrict__ We0h, const unsigned short* __restrict__ We0l,
        const float* __restrict__ b0,
        const unsigned short* __restrict__ We1h, const unsigned short* __restrict__ We1l,
        const float* __restrict__ b1,
        const int* __restrict__ batch,
        float* __restrict__ gfeat_part) {
    __shared__ float ldsT[4][16][133];
    __shared__ float poolw[4][64];
    __shared__ float pool[NG][64];
    const int tid = threadIdx.x;
    const int wave = tid >> 6;
    const int lane = tid & 63;
    const int rbase = blockIdx.x * 64 + wave * 16;

    int arow = rbase + (lane & 15);
    if (arow >= NN) arow = NN - 1;
    const int kbase = (lane >> 4) * 8;
    f32x4 acc[8];
#pragma unroll
    for (int f = 0; f < 8; f++) acc[f] = (f32x4){0.f, 0.f, 0.f, 0.f};

    const unsigned short* pa_hi = Hhi + (size_t)arow * HLD + kbase;
    const unsigned short* pa_lo = Hlo + (size_t)arow * HLD + kbase;

    bf16x8 cbh[8], cbl[8], nbh[8], nbl[8];
#pragma unroll
    for (int f = 0; f < 8; f++) {
        cbh[f] = *reinterpret_cast<const bf16x8*>(We0h + (size_t)(f * 64 + lane) * 8);
        cbl[f] = *reinterpret_cast<const bf16x8*>(We0l + (size_t)(f * 64 + lane) * 8);
    }
#pragma unroll
    for (int ks = 0; ks < 6; ks++) {
        if (ks < 5) {
#pragma unroll
            for (int f = 0; f < 8; f++) {
                nbh[f] = *reinterpret_cast<const bf16x8*>(We0h + (size_t)(((ks + 1) * 8 + f) * 64 + lane) * 8);
                nbl[f] = *reinterpret_cast<const bf16x8*>(We0l + (size_t)(((ks + 1) * 8 + f) * 64 + lane) * 8);
            }
        }
        bf16x8 ah = *reinterpret_cast<const bf16x8*>(pa_hi + ks * 32);
        bf16x8 al = *reinterpret_cast<const bf16x8*>(pa_lo + ks * 32);
#pragma unroll
        for (int f = 0; f < 8; f++) {
            acc[f] = __builtin_amdgcn_mfma_f32_16x16x32_bf16(ah, cbh[f], acc[f], 0, 0, 0);
            acc[f] = __builtin_amdgcn_mfma_f32_16x16x32_bf16(ah, cbl[f], acc[f], 0, 0, 0);
            acc[f] = __builtin_amdgcn_mfma_f32_16x16x32_bf16(al, cbh[f], acc[f], 0, 0, 0);
        }
        if (ks < 5) {
#pragma unroll
            for (int f = 0; f < 8; f++) { cbh[f] = nbh[f]; cbl[f] = nbl[f]; }
        }
    }

    const int lrow0 = (lane >> 4) * 4;
    const int dcol = lane & 15;
#pragma unroll
    for (int f = 0; f < 8; f++) {
#pragma unroll
        for (int r = 0; r < 4; r++) {
            float v = fmaxf(acc[f][r] + b0[f * 16 + dcol], 0.0f);
            ldsT[wave][lrow0 + r][f * 16 + dcol] = v;
        }
    }
    __syncthreads();

    bf16x8 wbh[4][4], wbl[4][4];
#pragma unroll
    for (int ks = 0; ks < 4; ks++)
#pragma unroll
        for (int f = 0; f < 4; f++) {
            wbh[ks][f] = *reinterpret_cast<const bf16x8*>(We1h + (size_t)((ks * 4 + f) * 64 + lane) * 8);
            wbl[ks][f] = *reinterpret_cast<const bf16x8*>(We1l + (size_t)((ks * 4 + f) * 64 + lane) * 8);
        }

    f32x4 acc2[4];
#pragma unroll
    for (int f = 0; f < 4; f++) acc2[f] = (f32x4){0.f, 0.f, 0.f, 0.f};

    const int trow = lane & 15;
#pragma unroll
    for (int ks = 0; ks < 4; ks++) {
        bf16x8 ah, al;
#pragma unroll
        for (int j = 0; j < 8; j++) {
            float tv = ldsT[wave][trow][ks * 32 + (lane >> 4) * 8 + j];
            unsigned short hi = f2bf(tv);
            ah[j] = (short)hi;
            al[j] = (short)f2bf(tv - bf2f(hi));
        }
#pragma unroll
        for (int f = 0; f < 4; f++) {
            acc2[f] = __builtin_amdgcn_mfma_f32_16x16x32_bf16(ah, wbh[ks][f], acc2[f], 0, 0, 0);
            acc2[f] = __builtin_amdgcn_mfma_f32_16x16x32_bf16(ah, wbl[ks][f], acc2[f], 0, 0, 0);
            acc2[f] = __builtin_amdgcn_mfma_f32_16x16x32_bf16(al, wbh[ks][f], acc2[f], 0, 0, 0);
        }
    }

    float vout[4][4];
#pragma unroll
    for (int f = 0; f < 4; f++)
#pragma unroll
        for (int r = 0; r < 4; r++) {
            int row = rbase + lrow0 + r;
            vout[f][r] = (row < NN) ? fmaxf(acc2[f][r] + b1[f * 16 + dcol], 0.0f) : 0.0f;
        }

    const int blk_row0 = blockIdx.x * 64;
    const int blk_rowN = min(blk_row0 + 63, NN - 1);
    const int g0 = batch[blk_row0];
    const int p = blockIdx.x & (NPART - 1);

    if (g0 == batch[blk_rowN]) {
#pragma unroll
        for (int f = 0; f < 4; f++) {
            float s = (vout[f][0] + vout[f][1]) + (vout[f][2] + vout[f][3]);
            s += __shfl_xor(s, 16, 64);
            s += __shfl_xor(s, 32, 64);
            if ((lane >> 4) == 0) poolw[wave][f * 16 + dcol] = s;
        }
        __syncthreads();
        if (tid < 64) {
            float s = (poolw[0][tid] + poolw[1][tid]) + (poolw[2][tid] + poolw[3][tid]);
            atomicAdd(&gfeat_part[(p * NG + g0) * 64 + tid], s);
        }
    } else {
        for (int i = tid; i < NG * 64; i += 256) ((float*)pool)[i] = 0.0f;
        __syncthreads();
#pragma unroll
        for (int r = 0; r < 4; r++) {
            int row = rbase + lrow0 + r;
            if (row < NN) {
                int g = batch[row];
#pragma unroll
                for (int f = 0; f < 4; f++)
                    atomicAdd(&pool[g][f * 16 + dcol], vout[f][r]);
            }
        }
        __syncthreads();
        for (int i = tid; i < NG * 64; i += 256) {
            float s = ((float*)pool)[i];
            if (s != 0.0f) atomicAdd(&gfeat_part[p * NG * 64 + i], s);
        }
    }
}

// ---------------- fp16-table gather + BN + ReLU -> hi/lo H slice ----------------

__global__ __launch_bounds__(256) void gather_bn_relu(
        const __half2* __restrict__ tab2,
        const int* __restrict__ rowptr,
        const unsigned short* __restrict__ esrc16,
        const float* __restrict__ dinv,
        const float* __restrict__ b, const float* __restrict__ g,
        const float* __restrict__ beta, const float* __restrict__ rm,
        const float* __restrict__ rv,
        unsigned short* __restrict__ Hhi, unsigned short* __restrict__ Hlo, int cbase) {
    const int wid = (blockIdx.x * 256 + threadIdx.x) >> 6;
    const int lane = threadIdx.x & 63;
    const int c2 = lane & 31;
    const int grp = lane >> 5;
    if (wid >= NN) return;
    const int beg = rowptr[wid], end = rowptr[wid + 1];
    float a0 = 0.0f, a1 = 0.0f;
    int e = beg + grp;
    for (; e + 14 < end; e += 16) {
        int s0 = esrc16[e],      s1 = esrc16[e + 2],  s2 = esrc16[e + 4],  s3 = esrc16[e + 6];
        int s4 = esrc16[e + 8],  s5 = esrc16[e + 10], s6 = esrc16[e + 12], s7 = esrc16[e + 14];
        float2 f0 = __half22float2(tab2[(size_t)s0 * 32 + c2]);
        float2 f1 = __half22float2(tab2[(size_t)s1 * 32 + c2]);
        float2 f2 = __half22float2(tab2[(size_t)s2 * 32 + c2]);
        float2 f3 = __half22float2(tab2[(size_t)s3 * 32 + c2]);
        float2 f4 = __half22float2(tab2[(size_t)s4 * 32 + c2]);
        float2 f5 = __half22float2(tab2[(size_t)s5 * 32 + c2]);
        float2 f6 = __half22float2(tab2[(size_t)s6 * 32 + c2]);
        float2 f7 = __half22float2(tab2[(size_t)s7 * 32 + c2]);
        a0 += ((f0.x + f1.x) + (f2.x + f3.x)) + ((f4.x + f5.x) + (f6.x + f7.x));
        a1 += ((f0.y + f1.y) + (f2.y + f3.y)) + ((f4.y + f5.y) + (f6.y + f7.y));
    }
    for (; e + 6 < end; e += 8) {
        int s0 = esrc16[e], s1 = esrc16[e + 2], s2 = esrc16[e + 4], s3 = esrc16[e + 6];
        float2 f0 = __half22float2(tab2[(size_t)s0 * 32 + c2]);
        float2 f1 = __half22float2(tab2[(size_t)s1 * 32 + c2]);
        float2 f2 = __half22float2(tab2[(size_t)s2 * 32 + c2]);
        float2 f3 = __half22float2(tab2[(size_t)s3 * 32 + c2]);
        a0 += (f0.x + f1.x) + (f2.x + f3.x);
        a1 += (f0.y + f1.y) + (f2.y + f3.y);
    }
    for (; e < end; e += 2) {
        float2 f = __half22float2(tab2[(size_t)esrc16[e] * 32 + c2]);
        a0 += f.x;
        a1 += f.y;
    }
    a0 += __shfl_xor(a0, 32, 64);
    a1 += __shfl_xor(a1, 32, 64);
    float2 fs = __half22float2(tab2[(size_t)wid * 32 + c2]);
    a0 += fs.x;
    a1 += fs.y;
    const float di = dinv[wid];
    a0 *= di;
    a1 *= di;
    const int ch0 = 2 * c2, ch1 = 2 * c2 + 1;
    float v0 = (a0 + b[ch0] - rm[ch0]) * (g[ch0] * rsqrtf(rv[ch0] + BN_EPS)) + beta[ch0];
    float v1 = (a1 + b[ch1] - rm[ch1]) * (g[ch1] * rsqrtf(rv[ch1] + BN_EPS)) + beta[ch1];
    v0 = fmaxf(v0, 0.0f);
    v1 = fmaxf(v1, 0.0f);
    if (grp == 0) {
        unsigned short h0 = f2bf(v0), h1 = f2bf(v1);
        unsigned short l0 = f2bf(v0 - bf2f(h0)), l1 = f2bf(v1 - bf2f(h1));
        size_t o = (size_t)wid * HLD + cbase + ch0;
        *reinterpret_cast<unsigned int*>(&Hhi[o]) = (unsigned int)h0 | ((unsigned int)h1 << 16);
        *reinterpret_cast<unsigned int*>(&Hlo[o]) = (unsigned int)l0 | ((unsigned int)l1 << 16);
    }
}

// ---------------- decoder ----------------

__global__ __launch_bounds__(256) void dec_kernel(
        const float* __restrict__ gfeat_part, const int* __restrict__ batch,
        const float* __restrict__ w0, const float* __restrict__ b0,
        const float* __restrict__ w1, const float* __restrict__ b1,
        float* __restrict__ out) {
    __shared__ float mg[NG][64];
    __shared__ float mc[NG];
    __shared__ float t1[NG][32];
    const int tid = threadIdx.x;
    for (int idx = tid; idx < NG * 64; idx += 256) {
        float s = 0.0f;
#pragma unroll
        for (int p = 0; p < NPART; p++) s += gfeat_part[p * NG * 64 + idx];
        mg[idx >> 6][idx & 63] = s;
    }
    if (tid < NG) {
        int lo = 0, hi = NN;
        while (lo < hi) { int m = (lo + hi) >> 1; if (batch[m] < tid) lo = m + 1; else hi = m; }
        int s0 = lo;
        lo = 0; hi = NN;
        while (lo < hi) { int m = (lo + hi) >> 1; if (batch[m] < tid + 1) lo = m + 1; else hi = m; }
        mc[tid] = (float)(lo - s0);
    }
    __syncthreads();
    const int g = tid >> 5, c = tid & 31;
    float inv = 1.0f / fmaxf(mc[g], 1.0f);
    float acc = b0[c];
    for (int k = 0; k < 64; k++)
        acc = fmaf(mg[g][k] * inv, w0[k * 32 + c], acc);
    t1[g][c] = fmaxf(acc, 0.0f);
    __syncthreads();
    if (tid < NG) {
        float o = b1[0];
        for (int c2 = 0; c2 < 32; c2++) o = fmaf(t1[tid][c2], w1[c2], o);
        out[tid] = o;
    }
}

// ---------------- launch ----------------

extern "C" void kernel_launch(void* const* d_in, const int* in_sizes, int n_in,
                              void* d_out, int out_size, void* d_ws, size_t ws_size,
                              hipStream_t stream) {
    const float* x      = (const float*)d_in[0];
    const int*   ei     = (const int*)d_in[1];
    const int*   batch  = (const int*)d_in[2];
    const float* W0     = (const float*)d_in[3];
    const float* b0     = (const float*)d_in[4];
    const float* g0     = (const float*)d_in[5];
    const float* beta0  = (const float*)d_in[6];
    const float* rm0    = (const float*)d_in[7];
    const float* rv0    = (const float*)d_in[8];
    const float* W1     = (const float*)d_in[9];
    const float* b1     = (const float*)d_in[10];
    const float* g1     = (const float*)d_in[11];
    const float* beta1  = (const float*)d_in[12];
    const float* rm1    = (const float*)d_in[13];
    const float* rv1    = (const float*)d_in[14];
    const float* W2     = (const float*)d_in[15];
    const float* b2     = (const float*)d_in[16];
    const float* g2     = (const float*)d_in[17];
    const float* beta2  = (const float*)d_in[18];
    const float* rm2    = (const float*)d_in[19];
    const float* rv2    = (const float*)d_in[20];
    const float* enc_w0 = (const float*)d_in[21];
    const float* enc_b0 = (const float*)d_in[22];
    const float* enc_w1 = (const float*)d_in[23];
    const float* enc_b1 = (const float*)d_in[24];
    const float* dec_w0 = (const float*)d_in[25];
    const float* dec_b0 = (const float*)d_in[26];
    const float* dec_w1 = (const float*)d_in[27];
    const float* dec_b1 = (const float*)d_in[28];

    const int* esrc = ei;
    const int* edst = ei + NE;

    char* wsb = (char*)d_ws;
    unsigned short* Hhi = (unsigned short*)wsb;                       // [NN*192]
    unsigned short* Hlo = Hhi + (size_t)NN * HLD;                     // [NN*192]
    int*   degi   = (int*)(Hlo + (size_t)NN * HLD);                   // [NN]
    int*   rowptr = degi + NN;                                        // [NN+1]
    int*   cursor = rowptr + NN + 1;                                  // [NN]
    unsigned short* esrc16 = (unsigned short*)(cursor + NN);          // [NE] u16
    __half* tabh  = (__half*)(esrc16 + NE);                           // [NN*64] fp16
    float* dinv   = (float*)(tabh + (size_t)NN * 64);                 // [NN]
    float* xs     = dinv + NN;                                        // [NN*3]
    float* gfeat_part = xs + (size_t)NN * 3;                          // [8*8*64]
    int*   bsum   = (int*)(gfeat_part + NPART * NG * 64);             // [NBLK]
    unsigned short* wp = (unsigned short*)(bsum + NBLK);
    unsigned short* Wp1h = wp;              unsigned short* Wp1l = Wp1h + 64 * 64;
    unsigned short* Wp2h = Wp1l + 64 * 64;  unsigned short* Wp2l = Wp2h + 128 * 64;
    unsigned short* We0h = Wp2l + 128 * 64; unsigned short* We0l = We0h + 192 * 128;
    unsigned short* We1h = We0l + 192 * 128;unsigned short* We1l = We1h + 128 * 64;

    const int GRID_MFMA = (NN + 63) / 64;
    const int GRID_64   = (NN * 64 + 255) / 256;
    const int GRID_PART = 8 * FC_NCHUNK;

    // pack weights + zero degi/gfeat (one dispatch, runs first)
    pack_all<<<NBLK, 256, 0, stream>>>(W1, W2, enc_w0, enc_w1,
                                       Wp1h, Wp1l, Wp2h, Wp2l,
                                       We0h, We0l, We1h, We1l, degi, gfeat_part);

    // CSR build (dst-partitioned for XCD-local atomics/scatter)
    count_deg_p<<<GRID_PART, 256, 0, stream>>>(edst, degi);
    scan_partial<<<NBLK, 256, 0, stream>>>(degi, x, rowptr, bsum, dinv, xs);
    scan_finalize<<<NBLK, 256, 0, stream>>>(bsum, rowptr, cursor);
    fill_csr_p<<<GRID_PART, 256, 0, stream>>>(esrc, edst, cursor, esrc16);

    // ---- layer 0 (fused aggregate + dense + BN + ReLU) ----
    agg_l0<<<GRID_64, 256, 0, stream>>>(xs, rowptr, esrc16, dinv,
                                        W0, b0, g0, beta0, rm0, rv0, Hhi, Hlo);

    // ---- layer 1 ----
    mfma_tab<64><<<GRID_MFMA, 256, 0, stream>>>(Hhi, Hlo, HLD, Wp1h, Wp1l, dinv, tabh);
    gather_bn_relu<<<GRID_64, 256, 0, stream>>>((const __half2*)tabh, rowptr, esrc16, dinv,
                                                b1, g1, beta1, rm1, rv1, Hhi, Hlo, 64);

    // ---- layer 2 ----
    mfma_tab<128><<<GRID_MFMA, 256, 0, stream>>>(Hhi, Hlo, HLD, Wp2h, Wp2l, dinv, tabh);
    gather_bn_relu<<<GRID_64, 256, 0, stream>>>((const __half2*)tabh, rowptr, esrc16, dinv,
                                                b2, g2, beta2, rm2, rv2, Hhi, Hlo, 128);

    // ---- fused encoder + pooling ----
    enc_fused<<<GRID_MFMA, 256, 0, stream>>>(Hhi, Hlo, We0h, We0l, enc_b0,
                                             We1h, We1l, enc_b1, batch, gfeat_part);

    // ---- decode ----
    dec_kernel<<<1, 256, 0, stream>>>(gfeat_part, batch, dec_w0, dec_b0, dec_w1, dec_b1, (float*)d_out);
}